// Round 7
// baseline (249.607 us; speedup 1.0000x reference)
//
#include <hip/hip_runtime.h>
#include <math.h>

#define N_NODES 1500
#define N_EDGES 12000
#define IN_FEAT 512
#define HIDDEN 64
#define OUT_FEAT 32
#define HEADS 8

typedef short bf16x8 __attribute__((ext_vector_type(8)));
typedef float f32x4 __attribute__((ext_vector_type(4)));

__device__ __forceinline__ unsigned short f2bf(float f) {
    unsigned u = __float_as_uint(f);
    u += 0x7fff + ((u >> 16) & 1);   // RNE
    return (unsigned short)(u >> 16);
}
__device__ __forceinline__ float bf2f(unsigned short b) {
    return __uint_as_float(((unsigned)b) << 16);
}
__device__ __forceinline__ unsigned packbf(float a) {
    unsigned short hi = f2bf(a);
    unsigned short lo = f2bf(a - bf2f(hi));
    return (unsigned)hi | ((unsigned)lo << 16);
}

// ---------------- fused prep: counts + att-eff vectors + W2 reshuffle + W3 MFMA frags ----
// W4t2 layout: W4t2[(kg*512 + c)*4 + j] = W2[(kg*4+j)*512 + c]
// wfrag3 layout: [(h*2+nt)*2+ks][lane][j] -> packed bf16 hi|lo of W3[ks*32+(l>>4)*8+j][h*32+nt*16+(l&15)]

__global__ void prep_kernel(const float* __restrict__ W2, const float* __restrict__ al2,
                            const float* __restrict__ ar2,
                            const float* __restrict__ W3, const float* __restrict__ al3,
                            const float* __restrict__ ar3,
                            float* __restrict__ aleff2, float* __restrict__ areff2,
                            float* __restrict__ aleff3, float* __restrict__ areff3,
                            float* __restrict__ W4t2, unsigned* __restrict__ wfrag3,
                            int* __restrict__ counts) {
    int i = blockIdx.x * blockDim.x + threadIdx.x;
    if (i < 1536) {
        if (i < N_NODES + 1) counts[i] = 0;
        return;
    }
    i -= 1536;
    if (i < 1024) {  // aleff2 / areff2: [h][64]
        int lr = i >> 9; i &= 511;
        int h = i >> 6, k = i & 63;
        const float* a = lr ? ar2 : al2;
        float s = 0.f;
        for (int f = 0; f < 64; ++f)
            s = fmaf(W2[(size_t)k * 512 + h * 64 + f], a[h * 64 + f], s);
        (lr ? areff2 : aleff2)[h * 64 + k] = s;
        return;
    }
    i -= 1024;
    if (i < 1024) {  // aleff3 / areff3
        int lr = i >> 9; i &= 511;
        int h = i >> 6, k = i & 63;
        const float* a = lr ? ar3 : al3;
        float s = 0.f;
        for (int f = 0; f < 32; ++f)
            s = fmaf(W3[(size_t)k * 256 + h * 32 + f], a[h * 32 + f], s);
        (lr ? areff3 : aleff3)[h * 64 + k] = s;
        return;
    }
    i -= 1024;
    if (i < 16 * 512 * 4) {  // W4t2
        int kg = i >> 11, rem = i & 2047;
        int c = rem >> 2, j = rem & 3;
        W4t2[i] = W2[(size_t)(kg * 4 + j) * 512 + c];
        return;
    }
    i -= 16 * 512 * 4;
    if (i < 16384) {  // wfrag3 (B-fragments for mfma_f32_16x16x32_bf16, hi/lo packed)
        int j = i & 7, l = (i >> 3) & 63;
        int ks = (i >> 9) & 1, nt = (i >> 10) & 1, h = (i >> 11) & 7;
        int k = ks * 32 + (l >> 4) * 8 + j;
        int col = h * 32 + nt * 16 + (l & 15);
        wfrag3[i] = packbf(W3[(size_t)k * 256 + col]);
    }
}

__global__ void hist_kernel(const int* __restrict__ dst, int* __restrict__ counts) {
    int e = blockIdx.x * blockDim.x + threadIdx.x;
    if (e < N_EDGES) atomicAdd(&counts[dst[e]], 1);
}

__global__ void scan_kernel(const int* __restrict__ counts, int* __restrict__ row_ptr) {
    __shared__ int part[256];
    int t = threadIdx.x;
    const int CH = (N_NODES + 255) / 256;
    int base = t * CH;
    int loc[8];
    int s = 0;
    for (int i = 0; i < CH; ++i) {
        int idx = base + i;
        int v = (idx < N_NODES) ? counts[idx] : 0;
        loc[i] = s;
        s += v;
    }
    part[t] = s;
    __syncthreads();
    if (t == 0) {
        int a = 0;
        for (int i = 0; i < 256; ++i) { int v = part[i]; part[i] = a; a += v; }
        row_ptr[N_NODES] = a;
    }
    __syncthreads();
    int p0 = part[t];
    for (int i = 0; i < CH; ++i) {
        int idx = base + i;
        if (idx < N_NODES) row_ptr[idx] = p0 + loc[i];
    }
}

// wave-per-node stable CSR build; stores SRC NODE ID directly.
__global__ void build_csr_kernel(const int* __restrict__ dst, const int* __restrict__ src,
                                 const int* __restrict__ row_ptr, int* __restrict__ csr_src) {
    int wid = (blockIdx.x * blockDim.x + threadIdx.x) >> 6;
    int lane = threadIdx.x & 63;
    if (wid >= N_NODES) return;
    int pos = row_ptr[wid];
    for (int base = 0; base < N_EDGES; base += 64) {
        int e = base + lane;
        bool hit = (e < N_EDGES) && (dst[e] == wid);
        unsigned long long m = __ballot(hit);
        if (hit) {
            int r = __popcll(m & ((1ull << lane) - 1ull));
            csr_src[pos + r] = src[e];
        }
        pos += __popcll(m);
    }
}

// ---------------- f32 tiled GEMM (layer 1): 32x32 tiles for occupancy (752 blocks) ----------

#define GM 32
#define GN 32
#define GK 32

__global__ __launch_bounds__(256) void gemm_f32(const float* __restrict__ A,
                                                const float* __restrict__ B,
                                                float* __restrict__ C,
                                                int M, int N, int K) {
    __shared__ float As[GK][GM + 2];
    __shared__ float Bs[GK][GN + 2];
    int t = threadIdx.x;
    int col0 = blockIdx.x * GN, row0 = blockIdx.y * GM;
    int tx = t & 15, ty = t >> 4;
    int am = t >> 3, ak = (t & 7) * 4;   // A: row am, k ak..ak+3
    int bk = t >> 3, bn = (t & 7) * 4;   // B: k row bk, cols bn..bn+3
    float acc[2][2] = {};
    for (int k0 = 0; k0 < K; k0 += GK) {
        int gr = row0 + am;
        float4 av = (gr < M) ? *(const float4*)&A[(size_t)gr * K + k0 + ak]
                             : make_float4(0.f, 0.f, 0.f, 0.f);
        float4 bv = *(const float4*)&B[(size_t)(k0 + bk) * N + col0 + bn];
        __syncthreads();
        As[ak + 0][am] = av.x; As[ak + 1][am] = av.y;
        As[ak + 2][am] = av.z; As[ak + 3][am] = av.w;
        *(float4*)&Bs[bk][bn] = bv;
        __syncthreads();
        #pragma unroll
        for (int kk = 0; kk < GK; ++kk) {
            float2 a2 = *(const float2*)&As[kk][ty * 2];
            float2 b2 = *(const float2*)&Bs[kk][tx * 2];
            acc[0][0] = fmaf(a2.x, b2.x, acc[0][0]);
            acc[0][1] = fmaf(a2.x, b2.y, acc[0][1]);
            acc[1][0] = fmaf(a2.y, b2.x, acc[1][0]);
            acc[1][1] = fmaf(a2.y, b2.y, acc[1][1]);
        }
    }
    #pragma unroll
    for (int i = 0; i < 2; ++i) {
        int gr = row0 + ty * 2 + i;
        if (gr < M) {
            float2 v = make_float2(acc[i][0], acc[i][1]);
            *(float2*)&C[(size_t)gr * N + col0 + tx * 2] = v;
        }
    }
}

// ---------------- el/er kernels ----------------

__global__ void elr_feat_kernel(const float* __restrict__ feat, const float* __restrict__ al,
                                const float* __restrict__ ar, float* __restrict__ el,
                                float* __restrict__ er, int RH) {
    int idx = blockIdx.x * blockDim.x + threadIdx.x;
    if (idx >= RH) return;
    int h = idx & (HEADS - 1);
    const float* fp = feat + (size_t)idx * HIDDEN;
    float sl = 0.f, sr = 0.f;
    for (int f = 0; f < HIDDEN; ++f) {
        float v = fp[f];
        sl = fmaf(v, al[h * HIDDEN + f], sl);
        sr = fmaf(v, ar[h * HIDDEN + f], sr);
    }
    el[idx] = sl;
    er[idx] = sr;
}

__global__ void elr_row_kernel(const float* __restrict__ X, const float* __restrict__ alv,
                               const float* __restrict__ arv, float* __restrict__ el,
                               float* __restrict__ er, int R) {
    int r = blockIdx.x * blockDim.x + threadIdx.x;
    if (r >= R) return;
    const float4* x4 = (const float4*)(X + (size_t)r * 64);
    float sl[8] = {}, sr[8] = {};
    for (int kg = 0; kg < 16; ++kg) {
        float4 xv = x4[kg];
        #pragma unroll
        for (int h = 0; h < 8; ++h) {
            float4 a = *(const float4*)&alv[h * 64 + kg * 4];
            float4 b = *(const float4*)&arv[h * 64 + kg * 4];
            sl[h] = fmaf(xv.x, a.x, fmaf(xv.y, a.y, fmaf(xv.z, a.z, fmaf(xv.w, a.w, sl[h]))));
            sr[h] = fmaf(xv.x, b.x, fmaf(xv.y, b.y, fmaf(xv.z, b.z, fmaf(xv.w, b.w, sr[h]))));
        }
    }
    float* elp = el + (size_t)r * 8;
    float* erp = er + (size_t)r * 8;
    #pragma unroll
    for (int h = 0; h < 8; ++h) { elp[h] = sl[h]; erp[h] = sr[h]; }
}

__device__ __forceinline__ float gelu_exact(float v) {
    return 0.5f * v * (1.0f + erff(v * 0.70710678118654752440f));
}

// ---------------- layer-1 aggregation: wave per (node, head-pair) ----------------
__global__ __launch_bounds__(256) void agg_l1(
    const float* __restrict__ feat, const float* __restrict__ el, const float* __restrict__ er,
    const float* __restrict__ bias, const int* __restrict__ row_ptr,
    const int* __restrict__ csr_src, float* __restrict__ out) {
    int n = blockIdx.x;
    int t = threadIdx.x, wv = t >> 6, lane = t & 63;
    int h0 = 2 * wv;
    int r0 = row_ptr[n], deg = row_ptr[n + 1] - r0;
    float2 erv = *(const float2*)&er[n * 8 + h0];
    float den0 = 0.f, den1 = 0.f, a0 = 0.f, a1 = 0.f;
    for (int i = 0; i < deg; ++i) {
        int s = csr_src[r0 + i];
        float2 elv = *(const float2*)&el[s * 8 + h0];
        float x0 = feat[((size_t)s * 8 + h0) * 64 + lane];
        float x1 = feat[((size_t)s * 8 + h0 + 1) * 64 + lane];
        float e0 = elv.x + erv.x; e0 = e0 > 0.f ? e0 : 0.2f * e0;
        float e1 = elv.y + erv.y; e1 = e1 > 0.f ? e1 : 0.2f * e1;
        float w0 = __expf(e0), w1 = __expf(e1);
        den0 += w0; den1 += w1;
        a0 = fmaf(w0, x0, a0);
        a1 = fmaf(w1, x1, a1);
    }
    float i0 = deg ? 1.f / den0 : 0.f;
    float i1 = deg ? 1.f / den1 : 0.f;
    float v0 = a0 * i0 + bias[h0 * 64 + lane];
    float v1 = a1 * i1 + bias[(h0 + 1) * 64 + lane];
    out[((size_t)n * 8 + h0) * 64 + lane] = gelu_exact(v0);
    out[((size_t)n * 8 + h0 + 1) * 64 + lane] = gelu_exact(v1);
}

// ---------------- layer 2: LDS-staged weights + register-blocked transform ----------------
template <int FOUT, bool GELU, int P>
__global__ __launch_bounds__(256, 4) void agg_fused4(
    const float* __restrict__ X,
    const float* __restrict__ el, const float* __restrict__ er,
    const float* __restrict__ W4t,
    const float* __restrict__ bias,
    const int* __restrict__ row_ptr, const int* __restrict__ csr_src,
    float* __restrict__ out)
{
    constexpr int TOT = 8 * FOUT;
    constexpr int KSPLIT = 2;
    constexpr int KGPT = 8;
    constexpr int FELEM = (FOUT == 32) ? 2 : 4;
    constexpr int FQn = FOUT / FELEM;
    constexpr int TPK = 8 * FQn;
    constexpr int FQ4 = FOUT / 4;
    constexpr int PTS = FOUT + 4;
    constexpr int WPFL = (KSPLIT * 64 * PTS > 64 * 64) ? KSPLIT * 64 * PTS : 64 * 64;
    constexpr int GRPS = P / 8;
    constexpr int CHUNK = 64;

    int nb = blockIdx.x;
    int n = nb / GRPS, pg = nb - n * GRPS;
    int p0 = pg * 8;
    int r0 = row_ptr[n], deg = row_ptr[n + 1] - r0;
    int t = threadIdx.x, wv = t >> 6, lane = t & 63;

    __shared__ int src_s[CHUNK];
    __shared__ float inv_s[64];
    __shared__ float acc_s[8][8][68];
    __shared__ float wp_lds[WPFL];

    float agg0[8], agg1[8];
    #pragma unroll
    for (int h = 0; h < 8; ++h) { agg0[h] = 0.f; agg1[h] = 0.f; }
    float den = 0.f;

    int elbase_n = (n * P + p0) * 8;
    int pA = p0 + wv * 2;

    for (int c0 = 0; c0 < deg; c0 += CHUNK) {
        int cnt = min(deg - c0, CHUNK);
        __syncthreads();
        if (t < cnt) src_s[t] = csr_src[r0 + c0 + t];
        for (int j = t; j < cnt * 64; j += 256) {
            int i = j >> 6, plh = j & 63;
            int s = csr_src[r0 + c0 + i];
            float e = el[(s * P + p0) * 8 + plh] + er[elbase_n + plh];
            e = e > 0.f ? e : 0.2f * e;
            wp_lds[i * 64 + plh] = __expf(e);
        }
        __syncthreads();
        if (t < 64) {
            for (int i = 0; i < cnt; ++i) den += wp_lds[i * 64 + t];
        }
        auto edge_fma = [&](int i) {
            int s = src_s[i];
            const float* wp = &wp_lds[i * 64 + wv * 16];
            float4 w0 = *(const float4*)wp;
            float4 w1 = *(const float4*)(wp + 4);
            float4 w2 = *(const float4*)(wp + 8);
            float4 w3 = *(const float4*)(wp + 12);
            int xb = (s * P + pA) * 64 + lane;
            float xv0 = X[xb];
            float xv1 = X[xb + 64];
            agg0[0] = fmaf(w0.x, xv0, agg0[0]);
            agg0[1] = fmaf(w0.y, xv0, agg0[1]);
            agg0[2] = fmaf(w0.z, xv0, agg0[2]);
            agg0[3] = fmaf(w0.w, xv0, agg0[3]);
            agg0[4] = fmaf(w1.x, xv0, agg0[4]);
            agg0[5] = fmaf(w1.y, xv0, agg0[5]);
            agg0[6] = fmaf(w1.z, xv0, agg0[6]);
            agg0[7] = fmaf(w1.w, xv0, agg0[7]);
            agg1[0] = fmaf(w2.x, xv1, agg1[0]);
            agg1[1] = fmaf(w2.y, xv1, agg1[1]);
            agg1[2] = fmaf(w2.z, xv1, agg1[2]);
            agg1[3] = fmaf(w2.w, xv1, agg1[3]);
            agg1[4] = fmaf(w3.x, xv1, agg1[4]);
            agg1[5] = fmaf(w3.y, xv1, agg1[5]);
            agg1[6] = fmaf(w3.z, xv1, agg1[6]);
            agg1[7] = fmaf(w3.w, xv1, agg1[7]);
        };
        int i = 0;
        for (; i + 2 <= cnt; i += 2) { edge_fma(i); edge_fma(i + 1); }
        if (i < cnt) edge_fma(i);
    }
    if (t < 64) inv_s[t] = deg ? 1.f / den : 0.f;
    __syncthreads();
    {
        int pl0 = wv * 2;
        #pragma unroll
        for (int h = 0; h < 8; ++h) {
            acc_s[pl0][h][lane] = agg0[h] * inv_s[pl0 * 8 + h];
            acc_s[pl0 + 1][h][lane] = agg1[h] * inv_s[pl0 * 8 + 8 + h];
        }
    }
    __syncthreads();

    {
        int kq = t / TPK;
        int rem = t - kq * TPK;
        int h = rem / FQn;
        int ft = rem - h * FQn;
        int f0 = ft * FELEM;
        float part[8][FELEM];
        #pragma unroll
        for (int pl = 0; pl < 8; ++pl)
            #pragma unroll
            for (int j = 0; j < FELEM; ++j) part[pl][j] = 0.f;
        #pragma unroll
        for (int kk = 0; kk < KGPT; ++kk) {
            int kg = kq * KGPT + kk;
            float4 wr[FELEM];
            #pragma unroll
            for (int j = 0; j < FELEM; ++j)
                wr[j] = *(const float4*)&W4t[(size_t)(kg * TOT + h * FOUT + f0 + j) * 4];
            #pragma unroll
            for (int pl = 0; pl < 8; ++pl) {
                float4 a4 = *(const float4*)&acc_s[pl][h][kg * 4];
                #pragma unroll
                for (int j = 0; j < FELEM; ++j)
                    part[pl][j] = fmaf(a4.x, wr[j].x, fmaf(a4.y, wr[j].y,
                                  fmaf(a4.z, wr[j].z, fmaf(a4.w, wr[j].w, part[pl][j]))));
            }
        }
        #pragma unroll
        for (int pl = 0; pl < 8; ++pl) {
            float* dstp = &wp_lds[((kq * 8 + pl) * 8 + h) * PTS + f0];
            if (FELEM == 4)
                *(float4*)dstp = make_float4(part[pl][0], part[pl][1], part[pl][2], part[pl][3]);
            else
                *(float2*)dstp = make_float2(part[pl][0], part[pl][1]);
        }
    }
    __syncthreads();

    {
        constexpr int NQ = 2 * TOT;
        for (int q = t; q < NQ; q += 256) {
            int pl = q / (TOT / 4);
            int rem = q - pl * (TOT / 4);
            int h = rem / FQ4, fq = rem - h * FQ4;
            int f0 = fq * 4;
            float4 acc4 = *(const float4*)&wp_lds[((0 * 8 + pl) * 8 + h) * PTS + f0];
            #pragma unroll
            for (int kq = 1; kq < KSPLIT; ++kq) {
                float4 pv = *(const float4*)&wp_lds[((kq * 8 + pl) * 8 + h) * PTS + f0];
                acc4.x += pv.x; acc4.y += pv.y; acc4.z += pv.z; acc4.w += pv.w;
            }
            float4 b4 = *(const float4*)&bias[h * FOUT + f0];
            acc4.x += b4.x; acc4.y += b4.y; acc4.z += b4.z; acc4.w += b4.w;
            if (GELU) {
                acc4.x = gelu_exact(acc4.x); acc4.y = gelu_exact(acc4.y);
                acc4.z = gelu_exact(acc4.z); acc4.w = gelu_exact(acc4.w);
            }
            *(float4*)&out[(size_t)(n * P + p0 + pl) * TOT + h * FOUT + f0] = acc4;
        }
    }
}

// ---------------- layer 3: aggregation + MFMA transform, 8p per block ----------------
// Block = (node, 8-p group), 12000 blocks. LDS ~26KB -> 6 blocks/CU.
// accP[h][pl<8][k] packed bf16 hi|lo; MFMA A rows 8-15 clamped (m16&7), never stored.
__global__ __launch_bounds__(256, 4) void agg_mfma3(
    const float* __restrict__ X,        // h2 [N*64, 64]
    const float* __restrict__ el, const float* __restrict__ er,  // [N*64, 8]
    const unsigned* __restrict__ wfrag, // [8h][2nt][2ks][64l][8j]
    const float* __restrict__ bias,     // [256]
    const int* __restrict__ row_ptr, const int* __restrict__ csr_src,
    float* __restrict__ out)            // [N*64, 256]
{
    constexpr int CHUNK = 32;
    int nb = blockIdx.x;                 // N_NODES * 8
    int n = nb >> 3, pg = nb & 7;
    int p0 = pg * 8;
    int r0 = row_ptr[n], deg = row_ptr[n + 1] - r0;
    int t = threadIdx.x, wv = t >> 6, lane = t & 63;

    __shared__ int src_s[CHUNK];
    __shared__ float w_s[CHUNK][64];       // [edge][pl*8+h]
    __shared__ float inv_s[64];
    __shared__ float er_s[64];
    __shared__ unsigned accP[8][8][68];    // [h][pl][k], stride 68 u32

    if (t < 64) er_s[t] = er[(size_t)(n * 64 + p0 + (t >> 3)) * 8 + (t & 7)];

    float den = 0.f;                       // t<64: (pl,h) = (t>>3, t&7)
    float agg[2][8];
    #pragma unroll
    for (int q = 0; q < 2; ++q)
        #pragma unroll
        for (int h = 0; h < 8; ++h) agg[q][h] = 0.f;
    int pA = p0 + wv * 2;

    for (int c0 = 0; c0 < deg; c0 += CHUNK) {
        int cnt = min(deg - c0, CHUNK);
        __syncthreads();
        if (t < cnt) src_s[t] = csr_src[r0 + c0 + t];
        for (int j = t; j < cnt * 64; j += 256) {
            int i = j >> 6, plh = j & 63;
            int s = csr_src[r0 + c0 + i];
            float e = el[(size_t)(s * 64 + p0) * 8 + plh] + er_s[plh];
            e = e > 0.f ? e : 0.2f * e;
            w_s[i][plh] = __expf(e);
        }
        __syncthreads();
        if (t < 64) {
            for (int i = 0; i < cnt; ++i) den += w_s[i][t];
        }
        for (int i = 0; i < cnt; ++i) {
            int s = src_s[i];
            const float* wp = &w_s[i][wv * 16];
            int xb = (s * 64 + pA) * 64 + lane;
            #pragma unroll
            for (int q = 0; q < 2; ++q) {
                float xv = X[xb + q * 64];
                float4 wa = *(const float4*)(wp + q * 8);
                float4 wb = *(const float4*)(wp + q * 8 + 4);
                agg[q][0] = fmaf(wa.x, xv, agg[q][0]);
                agg[q][1] = fmaf(wa.y, xv, agg[q][1]);
                agg[q][2] = fmaf(wa.z, xv, agg[q][2]);
                agg[q][3] = fmaf(wa.w, xv, agg[q][3]);
                agg[q][4] = fmaf(wb.x, xv, agg[q][4]);
                agg[q][5] = fmaf(wb.y, xv, agg[q][5]);
                agg[q][6] = fmaf(wb.z, xv, agg[q][6]);
                agg[q][7] = fmaf(wb.w, xv, agg[q][7]);
            }
        }
    }
    if (t < 64) inv_s[t] = deg ? 1.f / den : 0.f;
    __syncthreads();

    // scale + convert to packed bf16 hi/lo, write accP
    #pragma unroll
    for (int q = 0; q < 2; ++q) {
        int pl = wv * 2 + q;
        #pragma unroll
        for (int h = 0; h < 8; ++h) {
            float a = agg[q][h] * inv_s[pl * 8 + h];
            accP[h][pl][lane] = packbf(a);
        }
    }
    __syncthreads();

    // MFMA transform: wave wv handles heads 2wv, 2wv+1; A rows clamped to 8 p's.
    int m16 = lane & 15, g = lane >> 4;
    #pragma unroll
    for (int hh = 0; hh < 2; ++hh) {
        int h = wv * 2 + hh;
        bf16x8 a_hi[2], a_lo[2];
        #pragma unroll
        for (int ks = 0; ks < 2; ++ks) {
            const unsigned* ap = &accP[h][m16 & 7][ks * 32 + g * 8];
            uint4 q0 = *(const uint4*)ap;
            uint4 q1 = *(const uint4*)(ap + 4);
            a_hi[ks][0] = (short)(q0.x & 0xffffu); a_lo[ks][0] = (short)(q0.x >> 16);
            a_hi[ks][1] = (short)(q0.y & 0xffffu); a_lo[ks][1] = (short)(q0.y >> 16);
            a_hi[ks][2] = (short)(q0.z & 0xffffu); a_lo[ks][2] = (short)(q0.z >> 16);
            a_hi[ks][3] = (short)(q0.w & 0xffffu); a_lo[ks][3] = (short)(q0.w >> 16);
            a_hi[ks][4] = (short)(q1.x & 0xffffu); a_lo[ks][4] = (short)(q1.x >> 16);
            a_hi[ks][5] = (short)(q1.y & 0xffffu); a_lo[ks][5] = (short)(q1.y >> 16);
            a_hi[ks][6] = (short)(q1.z & 0xffffu); a_lo[ks][6] = (short)(q1.z >> 16);
            a_hi[ks][7] = (short)(q1.w & 0xffffu); a_lo[ks][7] = (short)(q1.w >> 16);
        }
        #pragma unroll
        for (int nt = 0; nt < 2; ++nt) {
            f32x4 D = {0.f, 0.f, 0.f, 0.f};
            #pragma unroll
            for (int ks = 0; ks < 2; ++ks) {
                const unsigned* bp = &wfrag[(size_t)(((h * 2 + nt) * 2 + ks) * 64 + lane) * 8];
                uint4 w0 = *(const uint4*)bp;
                uint4 w1 = *(const uint4*)(bp + 4);
                bf16x8 b_hi, b_lo;
                b_hi[0] = (short)(w0.x & 0xffffu); b_lo[0] = (short)(w0.x >> 16);
                b_hi[1] = (short)(w0.y & 0xffffu); b_lo[1] = (short)(w0.y >> 16);
                b_hi[2] = (short)(w0.z & 0xffffu); b_lo[2] = (short)(w0.z >> 16);
                b_hi[3] = (short)(w0.w & 0xffffu); b_lo[3] = (short)(w0.w >> 16);
                b_hi[4] = (short)(w1.x & 0xffffu); b_lo[4] = (short)(w1.x >> 16);
                b_hi[5] = (short)(w1.y & 0xffffu); b_lo[5] = (short)(w1.y >> 16);
                b_hi[6] = (short)(w1.z & 0xffffu); b_lo[6] = (short)(w1.z >> 16);
                b_hi[7] = (short)(w1.w & 0xffffu); b_lo[7] = (short)(w1.w >> 16);
                D = __builtin_amdgcn_mfma_f32_16x16x32_bf16(a_hi[ks], b_hi, D, 0, 0, 0);
                D = __builtin_amdgcn_mfma_f32_16x16x32_bf16(a_hi[ks], b_lo, D, 0, 0, 0);
                D = __builtin_amdgcn_mfma_f32_16x16x32_bf16(a_lo[ks], b_hi, D, 0, 0, 0);
            }
            if (g < 2) {
                float bv = bias[h * 32 + nt * 16 + m16];
                size_t ob = ((size_t)(n * 64) + p0 + g * 4) * 256 + h * 32 + nt * 16 + m16;
                out[ob]       = D[0] + bv;
                out[ob + 256] = D[1] + bv;
                out[ob + 512] = D[2] + bv;
                out[ob + 768] = D[3] + bv;
            }
        }
    }
}

// ---------------- launch ----------------

extern "C" void kernel_launch(void* const* d_in, const int* in_sizes, int n_in,
                              void* d_out, int out_size, void* d_ws, size_t ws_size,
                              hipStream_t stream) {
    const float* node = (const float*)d_in[0];
    const int* src = (const int*)d_in[1];
    const int* dst = (const int*)d_in[2];
    const float* W1 = (const float*)d_in[3];
    const float* al1 = (const float*)d_in[4];
    const float* ar1 = (const float*)d_in[5];
    const float* b1 = (const float*)d_in[6];
    const float* W2 = (const float*)d_in[7];
    const float* al2 = (const float*)d_in[8];
    const float* ar2 = (const float*)d_in[9];
    const float* b2 = (const float*)d_in[10];
    const float* W3 = (const float*)d_in[11];
    const float* al3 = (const float*)d_in[12];
    const float* ar3 = (const float*)d_in[13];
    const float* b3 = (const float*)d_in[14];
    float* out = (float*)d_out;

    char* ws = (char*)d_ws;
    size_t off = 0;
    auto alloc = [&](size_t nb) -> char* {
        char* q = ws + off;
        off += (nb + 255) & ~(size_t)255;
        return q;
    };
    int* counts   = (int*)alloc((N_NODES + 1) * sizeof(int));
    int* row_ptr  = (int*)alloc((N_NODES + 1) * sizeof(int));
    int* csr_src  = (int*)alloc(N_EDGES * sizeof(int));
    float* feat1  = (float*)alloc((size_t)N_NODES * 8 * 64 * 4);
    float* el1    = (float*)alloc((size_t)N_NODES * 8 * 4);
    float* er1    = (float*)alloc((size_t)N_NODES * 8 * 4);
    float* h1     = (float*)alloc((size_t)N_NODES * 8 * 64 * 4);
    float* aleff2 = (float*)alloc(8 * 64 * 4);
    float* areff2 = (float*)alloc(8 * 64 * 4);
    float* el2    = (float*)alloc((size_t)N_NODES * 8 * 8 * 4);
    float* er2    = (float*)alloc((size_t)N_NODES * 8 * 8 * 4);
    float* h2     = (float*)alloc((size_t)N_NODES * 64 * 64 * 4);
    float* aleff3 = (float*)alloc(8 * 64 * 4);
    float* areff3 = (float*)alloc(8 * 64 * 4);
    float* el3    = (float*)alloc((size_t)N_NODES * 64 * 8 * 4);
    float* er3    = (float*)alloc((size_t)N_NODES * 64 * 8 * 4);
    float* W4t2   = (float*)alloc((size_t)16 * 512 * 4 * 4);
    unsigned* wfrag3 = (unsigned*)alloc((size_t)16384 * 4);

    const int PREP_T = 1536 + 1024 + 1024 + 16 * 512 * 4 + 16384;
    prep_kernel<<<(PREP_T + 255) / 256, 256, 0, stream>>>(
        W2, al2, ar2, W3, al3, ar3, aleff2, areff2, aleff3, areff3, W4t2, wfrag3, counts);

    hist_kernel<<<(N_EDGES + 255) / 256, 256, 0, stream>>>(dst, counts);
    scan_kernel<<<1, 256, 0, stream>>>(counts, row_ptr);
    build_csr_kernel<<<(N_NODES * 64 + 255) / 256, 256, 0, stream>>>(dst, src, row_ptr, csr_src);

    // ---- layer 1 ----
    dim3 g1((512 + GN - 1) / GN, (N_NODES + GM - 1) / GM);
    gemm_f32<<<g1, 256, 0, stream>>>(node, W1, feat1, N_NODES, 512, IN_FEAT);
    elr_feat_kernel<<<(N_NODES * 8 + 255) / 256, 256, 0, stream>>>(feat1, al1, ar1, el1, er1, N_NODES * 8);
    agg_l1<<<N_NODES, 256, 0, stream>>>(feat1, el1, er1, b1, row_ptr, csr_src, h1);

    // ---- layer 2 ----
    elr_row_kernel<<<(N_NODES * 8 + 255) / 256, 256, 0, stream>>>(h1, aleff2, areff2, el2, er2, N_NODES * 8);
    agg_fused4<64, true, 8><<<N_NODES, 256, 0, stream>>>(h1, el2, er2, W4t2, b2, row_ptr, csr_src, h2);

    // ---- layer 3 ----
    elr_row_kernel<<<(N_NODES * 64 + 255) / 256, 256, 0, stream>>>(h2, aleff3, areff3, el3, er3, N_NODES * 64);
    agg_mfma3<<<N_NODES * 8, 256, 0, stream>>>(h2, el3, er3, wfrag3, b3, row_ptr, csr_src, out);
}

// Round 8
// 177.399 us; speedup vs baseline: 1.4070x; 1.4070x over previous
//
#include <hip/hip_runtime.h>
#include <math.h>

#define N_NODES 1500
#define N_EDGES 12000
#define IN_FEAT 512
#define HIDDEN 64
#define OUT_FEAT 32
#define HEADS 8

typedef short bf16x8 __attribute__((ext_vector_type(8)));
typedef float f32x4 __attribute__((ext_vector_type(4)));

__device__ __forceinline__ unsigned short f2bf(float f) {
    unsigned u = __float_as_uint(f);
    u += 0x7fff + ((u >> 16) & 1);   // RNE
    return (unsigned short)(u >> 16);
}
__device__ __forceinline__ float bf2f(unsigned short b) {
    return __uint_as_float(((unsigned)b) << 16);
}
__device__ __forceinline__ unsigned packbf(float a) {
    unsigned short hi = f2bf(a);
    unsigned short lo = f2bf(a - bf2f(hi));
    return (unsigned)hi | ((unsigned)lo << 16);
}
__device__ __forceinline__ float rdlane(float v, int c) {
    return __uint_as_float(__builtin_amdgcn_readlane(__float_as_uint(v), c));
}

// ---------------- fused prep: counts/cursor zero + att-eff vectors + W2 reshuffle + W3 frags
// W4t2 layout: W4t2[(kg*512 + c)*4 + j] = W2[(kg*4+j)*512 + c]
// wfrag3 layout: [(h*2+nt)*2+ks][lane][j] -> packed bf16 hi|lo of W3[ks*32+(l>>4)*8+j][h*32+nt*16+(l&15)]

__global__ void prep_kernel(const float* __restrict__ W2, const float* __restrict__ al2,
                            const float* __restrict__ ar2,
                            const float* __restrict__ W3, const float* __restrict__ al3,
                            const float* __restrict__ ar3,
                            float* __restrict__ aleff2, float* __restrict__ areff2,
                            float* __restrict__ aleff3, float* __restrict__ areff3,
                            float* __restrict__ W4t2, unsigned* __restrict__ wfrag3,
                            int* __restrict__ counts, int* __restrict__ cursor) {
    int i = blockIdx.x * blockDim.x + threadIdx.x;
    if (i < 1536) {
        if (i < N_NODES + 1) counts[i] = 0;
        return;
    }
    i -= 1536;
    if (i < 1536) {
        if (i < N_NODES) cursor[i] = 0;
        return;
    }
    i -= 1536;
    if (i < 1024) {  // aleff2 / areff2: [h][64]
        int lr = i >> 9; i &= 511;
        int h = i >> 6, k = i & 63;
        const float* a = lr ? ar2 : al2;
        float s = 0.f;
        for (int f = 0; f < 64; ++f)
            s = fmaf(W2[(size_t)k * 512 + h * 64 + f], a[h * 64 + f], s);
        (lr ? areff2 : aleff2)[h * 64 + k] = s;
        return;
    }
    i -= 1024;
    if (i < 1024) {  // aleff3 / areff3
        int lr = i >> 9; i &= 511;
        int h = i >> 6, k = i & 63;
        const float* a = lr ? ar3 : al3;
        float s = 0.f;
        for (int f = 0; f < 32; ++f)
            s = fmaf(W3[(size_t)k * 256 + h * 32 + f], a[h * 32 + f], s);
        (lr ? areff3 : aleff3)[h * 64 + k] = s;
        return;
    }
    i -= 1024;
    if (i < 16 * 512 * 4) {  // W4t2
        int kg = i >> 11, rem = i & 2047;
        int c = rem >> 2, j = rem & 3;
        W4t2[i] = W2[(size_t)(kg * 4 + j) * 512 + c];
        return;
    }
    i -= 16 * 512 * 4;
    if (i < 16384) {  // wfrag3 (B-fragments for mfma_f32_16x16x32_bf16, hi/lo packed)
        int j = i & 7, l = (i >> 3) & 63;
        int ks = (i >> 9) & 1, nt = (i >> 10) & 1, h = (i >> 11) & 7;
        int k = ks * 32 + (l >> 4) * 8 + j;
        int col = h * 32 + nt * 16 + (l & 15);
        wfrag3[i] = packbf(W3[(size_t)k * 256 + col]);
    }
}

__global__ void hist_kernel(const int* __restrict__ dst, int* __restrict__ counts) {
    int e = blockIdx.x * blockDim.x + threadIdx.x;
    if (e < N_EDGES) atomicAdd(&counts[dst[e]], 1);
}

__global__ void scan_kernel(const int* __restrict__ counts, int* __restrict__ row_ptr) {
    __shared__ int part[256];
    int t = threadIdx.x;
    const int CH = (N_NODES + 255) / 256;
    int base = t * CH;
    int loc[8];
    int s = 0;
    for (int i = 0; i < CH; ++i) {
        int idx = base + i;
        int v = (idx < N_NODES) ? counts[idx] : 0;
        loc[i] = s;
        s += v;
    }
    part[t] = s;
    __syncthreads();
    if (t == 0) {
        int a = 0;
        for (int i = 0; i < 256; ++i) { int v = part[i]; part[i] = a; a += v; }
        row_ptr[N_NODES] = a;
    }
    __syncthreads();
    int p0 = part[t];
    for (int i = 0; i < CH; ++i) {
        int idx = base + i;
        if (idx < N_NODES) row_ptr[idx] = p0 + loc[i];
    }
}

// atomic scatter of edge ids (order nondeterministic) ...
__global__ void scatter_kernel(const int* __restrict__ dst, const int* __restrict__ row_ptr,
                               int* __restrict__ cursor, int* __restrict__ tmp_eid) {
    int e = blockIdx.x * blockDim.x + threadIdx.x;
    if (e < N_EDGES) {
        int d = dst[e];
        int pos = row_ptr[d] + atomicAdd(&cursor[d], 1);
        tmp_eid[pos] = e;
    }
}

// ... then per-node sort by edge id restores the deterministic stable order.
__global__ void sort_csr_kernel(const int* __restrict__ row_ptr, const int* __restrict__ tmp_eid,
                                const int* __restrict__ src, int* __restrict__ csr_src) {
    int wid = (blockIdx.x * blockDim.x + threadIdx.x) >> 6;
    int lane = threadIdx.x & 63;
    if (wid >= N_NODES) return;
    int r0 = row_ptr[wid], deg = row_ptr[wid + 1] - r0;
    for (int base = 0; base < deg; base += 64) {
        int i = base + lane;
        int my = (i < deg) ? tmp_eid[r0 + i] : 0x7fffffff;
        int rank = 0;
        for (int b2 = 0; b2 < deg; b2 += 64) {
            int other = (b2 + lane < deg) ? tmp_eid[r0 + b2 + lane] : 0x7fffffff;
            int cnt2 = min(deg - b2, 64);
            for (int j = 0; j < cnt2; ++j) {
                int oj = __shfl(other, j);
                rank += (oj < my) ? 1 : 0;
            }
        }
        if (i < deg) csr_src[r0 + rank] = src[my];
    }
}

// ---------------- f32 tiled GEMM (layer 1): 32x32 tiles (752 blocks) ----------

#define GM 32
#define GN 32
#define GK 32

__global__ __launch_bounds__(256) void gemm_f32(const float* __restrict__ A,
                                                const float* __restrict__ B,
                                                float* __restrict__ C,
                                                int M, int N, int K) {
    __shared__ float As[GK][GM + 2];
    __shared__ float Bs[GK][GN + 2];
    int t = threadIdx.x;
    int col0 = blockIdx.x * GN, row0 = blockIdx.y * GM;
    int tx = t & 15, ty = t >> 4;
    int am = t >> 3, ak = (t & 7) * 4;
    int bk = t >> 3, bn = (t & 7) * 4;
    float acc[2][2] = {};
    for (int k0 = 0; k0 < K; k0 += GK) {
        int gr = row0 + am;
        float4 av = (gr < M) ? *(const float4*)&A[(size_t)gr * K + k0 + ak]
                             : make_float4(0.f, 0.f, 0.f, 0.f);
        float4 bv = *(const float4*)&B[(size_t)(k0 + bk) * N + col0 + bn];
        __syncthreads();
        As[ak + 0][am] = av.x; As[ak + 1][am] = av.y;
        As[ak + 2][am] = av.z; As[ak + 3][am] = av.w;
        *(float4*)&Bs[bk][bn] = bv;
        __syncthreads();
        #pragma unroll
        for (int kk = 0; kk < GK; ++kk) {
            float2 a2 = *(const float2*)&As[kk][ty * 2];
            float2 b2 = *(const float2*)&Bs[kk][tx * 2];
            acc[0][0] = fmaf(a2.x, b2.x, acc[0][0]);
            acc[0][1] = fmaf(a2.x, b2.y, acc[0][1]);
            acc[1][0] = fmaf(a2.y, b2.x, acc[1][0]);
            acc[1][1] = fmaf(a2.y, b2.y, acc[1][1]);
        }
    }
    #pragma unroll
    for (int i = 0; i < 2; ++i) {
        int gr = row0 + ty * 2 + i;
        if (gr < M) {
            float2 v = make_float2(acc[i][0], acc[i][1]);
            *(float2*)&C[(size_t)gr * N + col0 + tx * 2] = v;
        }
    }
}

// ---------------- el/er kernels ----------------

__global__ void elr_feat_kernel(const float* __restrict__ feat, const float* __restrict__ al,
                                const float* __restrict__ ar, float* __restrict__ el,
                                float* __restrict__ er, int RH) {
    int idx = blockIdx.x * blockDim.x + threadIdx.x;
    if (idx >= RH) return;
    int h = idx & (HEADS - 1);
    const float* fp = feat + (size_t)idx * HIDDEN;
    float sl = 0.f, sr = 0.f;
    for (int f = 0; f < HIDDEN; ++f) {
        float v = fp[f];
        sl = fmaf(v, al[h * HIDDEN + f], sl);
        sr = fmaf(v, ar[h * HIDDEN + f], sr);
    }
    el[idx] = sl;
    er[idx] = sr;
}

__global__ void elr_row_kernel(const float* __restrict__ X, const float* __restrict__ alv,
                               const float* __restrict__ arv, float* __restrict__ el,
                               float* __restrict__ er, int R) {
    int r = blockIdx.x * blockDim.x + threadIdx.x;
    if (r >= R) return;
    const float4* x4 = (const float4*)(X + (size_t)r * 64);
    float sl[8] = {}, sr[8] = {};
    for (int kg = 0; kg < 16; ++kg) {
        float4 xv = x4[kg];
        #pragma unroll
        for (int h = 0; h < 8; ++h) {
            float4 a = *(const float4*)&alv[h * 64 + kg * 4];
            float4 b = *(const float4*)&arv[h * 64 + kg * 4];
            sl[h] = fmaf(xv.x, a.x, fmaf(xv.y, a.y, fmaf(xv.z, a.z, fmaf(xv.w, a.w, sl[h]))));
            sr[h] = fmaf(xv.x, b.x, fmaf(xv.y, b.y, fmaf(xv.z, b.z, fmaf(xv.w, b.w, sr[h]))));
        }
    }
    float* elp = el + (size_t)r * 8;
    float* erp = er + (size_t)r * 8;
    #pragma unroll
    for (int h = 0; h < 8; ++h) { elp[h] = sl[h]; erp[h] = sr[h]; }
}

__device__ __forceinline__ float gelu_exact(float v) {
    return 0.5f * v * (1.0f + erff(v * 0.70710678118654752440f));
}

// ---------------- layer-1 aggregation: wave per (node, head-pair) ----------------
__global__ __launch_bounds__(256) void agg_l1(
    const float* __restrict__ feat, const float* __restrict__ el, const float* __restrict__ er,
    const float* __restrict__ bias, const int* __restrict__ row_ptr,
    const int* __restrict__ csr_src, float* __restrict__ out) {
    int n = blockIdx.x;
    int t = threadIdx.x, wv = t >> 6, lane = t & 63;
    int h0 = 2 * wv;
    int r0 = row_ptr[n], deg = row_ptr[n + 1] - r0;
    float2 erv = *(const float2*)&er[n * 8 + h0];
    float den0 = 0.f, den1 = 0.f, a0 = 0.f, a1 = 0.f;
    for (int i = 0; i < deg; ++i) {
        int s = csr_src[r0 + i];
        float2 elv = *(const float2*)&el[s * 8 + h0];
        float x0 = feat[((size_t)s * 8 + h0) * 64 + lane];
        float x1 = feat[((size_t)s * 8 + h0 + 1) * 64 + lane];
        float e0 = elv.x + erv.x; e0 = e0 > 0.f ? e0 : 0.2f * e0;
        float e1 = elv.y + erv.y; e1 = e1 > 0.f ? e1 : 0.2f * e1;
        float w0 = __expf(e0), w1 = __expf(e1);
        den0 += w0; den1 += w1;
        a0 = fmaf(w0, x0, a0);
        a1 = fmaf(w1, x1, a1);
    }
    float i0 = deg ? 1.f / den0 : 0.f;
    float i1 = deg ? 1.f / den1 : 0.f;
    float v0 = a0 * i0 + bias[h0 * 64 + lane];
    float v1 = a1 * i1 + bias[(h0 + 1) * 64 + lane];
    out[((size_t)n * 8 + h0) * 64 + lane] = gelu_exact(v0);
    out[((size_t)n * 8 + h0 + 1) * 64 + lane] = gelu_exact(v1);
}

// ---------------- layer 2: LDS-staged weights + register-blocked transform ----------------
template <int FOUT, bool GELU, int P>
__global__ __launch_bounds__(256, 4) void agg_fused4(
    const float* __restrict__ X,
    const float* __restrict__ el, const float* __restrict__ er,
    const float* __restrict__ W4t,
    const float* __restrict__ bias,
    const int* __restrict__ row_ptr, const int* __restrict__ csr_src,
    float* __restrict__ out)
{
    constexpr int TOT = 8 * FOUT;
    constexpr int KSPLIT = 2;
    constexpr int KGPT = 8;
    constexpr int FELEM = (FOUT == 32) ? 2 : 4;
    constexpr int FQn = FOUT / FELEM;
    constexpr int TPK = 8 * FQn;
    constexpr int FQ4 = FOUT / 4;
    constexpr int PTS = FOUT + 4;
    constexpr int WPFL = (KSPLIT * 64 * PTS > 64 * 64) ? KSPLIT * 64 * PTS : 64 * 64;
    constexpr int GRPS = P / 8;
    constexpr int CHUNK = 64;

    int nb = blockIdx.x;
    int n = nb / GRPS, pg = nb - n * GRPS;
    int p0 = pg * 8;
    int r0 = row_ptr[n], deg = row_ptr[n + 1] - r0;
    int t = threadIdx.x, wv = t >> 6, lane = t & 63;

    __shared__ int src_s[CHUNK];
    __shared__ float inv_s[64];
    __shared__ float acc_s[8][8][68];
    __shared__ float wp_lds[WPFL];

    float agg0[8], agg1[8];
    #pragma unroll
    for (int h = 0; h < 8; ++h) { agg0[h] = 0.f; agg1[h] = 0.f; }
    float den = 0.f;

    int elbase_n = (n * P + p0) * 8;
    int pA = p0 + wv * 2;

    for (int c0 = 0; c0 < deg; c0 += CHUNK) {
        int cnt = min(deg - c0, CHUNK);
        __syncthreads();
        if (t < cnt) src_s[t] = csr_src[r0 + c0 + t];
        for (int j = t; j < cnt * 64; j += 256) {
            int i = j >> 6, plh = j & 63;
            int s = csr_src[r0 + c0 + i];
            float e = el[(s * P + p0) * 8 + plh] + er[elbase_n + plh];
            e = e > 0.f ? e : 0.2f * e;
            wp_lds[i * 64 + plh] = __expf(e);
        }
        __syncthreads();
        if (t < 64) {
            for (int i = 0; i < cnt; ++i) den += wp_lds[i * 64 + t];
        }
        auto edge_fma = [&](int i) {
            int s = src_s[i];
            const float* wp = &wp_lds[i * 64 + wv * 16];
            float4 w0 = *(const float4*)wp;
            float4 w1 = *(const float4*)(wp + 4);
            float4 w2 = *(const float4*)(wp + 8);
            float4 w3 = *(const float4*)(wp + 12);
            int xb = (s * P + pA) * 64 + lane;
            float xv0 = X[xb];
            float xv1 = X[xb + 64];
            agg0[0] = fmaf(w0.x, xv0, agg0[0]);
            agg0[1] = fmaf(w0.y, xv0, agg0[1]);
            agg0[2] = fmaf(w0.z, xv0, agg0[2]);
            agg0[3] = fmaf(w0.w, xv0, agg0[3]);
            agg0[4] = fmaf(w1.x, xv0, agg0[4]);
            agg0[5] = fmaf(w1.y, xv0, agg0[5]);
            agg0[6] = fmaf(w1.z, xv0, agg0[6]);
            agg0[7] = fmaf(w1.w, xv0, agg0[7]);
            agg1[0] = fmaf(w2.x, xv1, agg1[0]);
            agg1[1] = fmaf(w2.y, xv1, agg1[1]);
            agg1[2] = fmaf(w2.z, xv1, agg1[2]);
            agg1[3] = fmaf(w2.w, xv1, agg1[3]);
            agg1[4] = fmaf(w3.x, xv1, agg1[4]);
            agg1[5] = fmaf(w3.y, xv1, agg1[5]);
            agg1[6] = fmaf(w3.z, xv1, agg1[6]);
            agg1[7] = fmaf(w3.w, xv1, agg1[7]);
        };
        int i = 0;
        for (; i + 2 <= cnt; i += 2) { edge_fma(i); edge_fma(i + 1); }
        if (i < cnt) edge_fma(i);
    }
    if (t < 64) inv_s[t] = deg ? 1.f / den : 0.f;
    __syncthreads();
    {
        int pl0 = wv * 2;
        #pragma unroll
        for (int h = 0; h < 8; ++h) {
            acc_s[pl0][h][lane] = agg0[h] * inv_s[pl0 * 8 + h];
            acc_s[pl0 + 1][h][lane] = agg1[h] * inv_s[pl0 * 8 + 8 + h];
        }
    }
    __syncthreads();

    {
        int kq = t / TPK;
        int rem = t - kq * TPK;
        int h = rem / FQn;
        int ft = rem - h * FQn;
        int f0 = ft * FELEM;
        float part[8][FELEM];
        #pragma unroll
        for (int pl = 0; pl < 8; ++pl)
            #pragma unroll
            for (int j = 0; j < FELEM; ++j) part[pl][j] = 0.f;
        #pragma unroll
        for (int kk = 0; kk < KGPT; ++kk) {
            int kg = kq * KGPT + kk;
            float4 wr[FELEM];
            #pragma unroll
            for (int j = 0; j < FELEM; ++j)
                wr[j] = *(const float4*)&W4t[(size_t)(kg * TOT + h * FOUT + f0 + j) * 4];
            #pragma unroll
            for (int pl = 0; pl < 8; ++pl) {
                float4 a4 = *(const float4*)&acc_s[pl][h][kg * 4];
                #pragma unroll
                for (int j = 0; j < FELEM; ++j)
                    part[pl][j] = fmaf(a4.x, wr[j].x, fmaf(a4.y, wr[j].y,
                                  fmaf(a4.z, wr[j].z, fmaf(a4.w, wr[j].w, part[pl][j]))));
            }
        }
        #pragma unroll
        for (int pl = 0; pl < 8; ++pl) {
            float* dstp = &wp_lds[((kq * 8 + pl) * 8 + h) * PTS + f0];
            if (FELEM == 4)
                *(float4*)dstp = make_float4(part[pl][0], part[pl][1], part[pl][2], part[pl][3]);
            else
                *(float2*)dstp = make_float2(part[pl][0], part[pl][1]);
        }
    }
    __syncthreads();

    {
        constexpr int NQ = 2 * TOT;
        for (int q = t; q < NQ; q += 256) {
            int pl = q / (TOT / 4);
            int rem = q - pl * (TOT / 4);
            int h = rem / FQ4, fq = rem - h * FQ4;
            int f0 = fq * 4;
            float4 acc4 = *(const float4*)&wp_lds[((0 * 8 + pl) * 8 + h) * PTS + f0];
            #pragma unroll
            for (int kq = 1; kq < KSPLIT; ++kq) {
                float4 pv = *(const float4*)&wp_lds[((kq * 8 + pl) * 8 + h) * PTS + f0];
                acc4.x += pv.x; acc4.y += pv.y; acc4.z += pv.z; acc4.w += pv.w;
            }
            float4 b4 = *(const float4*)&bias[h * FOUT + f0];
            acc4.x += b4.x; acc4.y += b4.y; acc4.z += b4.z; acc4.w += b4.w;
            if (GELU) {
                acc4.x = gelu_exact(acc4.x); acc4.y = gelu_exact(acc4.y);
                acc4.z = gelu_exact(acc4.z); acc4.w = gelu_exact(acc4.w);
            }
            *(float4*)&out[(size_t)(n * P + p0 + pl) * TOT + h * FOUT + f0] = acc4;
        }
    }
}

// ---------------- layer 3: barrier-free readlane aggregation + MFMA transform ----------------
// Block = (node, 16-p group), 6000 blocks, LDS = accP only (34.8 KB) -> 4 blocks/CU.
// Lanes 0-31 compute the 32 (q,h) weights for edge i, lanes 32-63 for edge i+1;
// broadcast via v_readlane (SGPR in FMA). One barrier per block.
__global__ __launch_bounds__(256, 4) void agg_mfma5(
    const float* __restrict__ X,        // h2 [N*64, 64]
    const float* __restrict__ el, const float* __restrict__ er,  // [N*64, 8]
    const unsigned* __restrict__ wfrag, // [8h][2nt][2ks][64l][8j]
    const float* __restrict__ bias,     // [256]
    const int* __restrict__ row_ptr, const int* __restrict__ csr_src,
    float* __restrict__ out)            // [N*64, 256]
{
    int nb = blockIdx.x;                 // N_NODES * 4
    int n = nb >> 2, pg = nb & 3;
    int p0 = pg * 16;
    int r0 = row_ptr[n], deg = row_ptr[n + 1] - r0;
    int t = threadIdx.x, wv = t >> 6, lane = t & 63;
    int pA = p0 + wv * 4;

    __shared__ unsigned accP[8][16][68];   // [h][pl][k] packed bf16 hi|lo

    int c = lane & 31;                     // (q,h) = (c>>3, c&7)
    float erv = er[(n * 64 + pA) * 8 + c];

    float agg[4][8];
    #pragma unroll
    for (int q = 0; q < 4; ++q)
        #pragma unroll
        for (int h = 0; h < 8; ++h) agg[q][h] = 0.f;
    float den_half = 0.f;

    for (int it = 0; it < deg; it += 2) {
        int s0 = csr_src[r0 + it];
        bool v1 = (it + 1 < deg);
        int s1 = v1 ? csr_src[r0 + it + 1] : s0;
        // weights: half-wave per edge
        int sw = (lane < 32) ? s0 : s1;
        float e = el[(sw * 64 + pA) * 8 + c] + erv;
        e = e > 0.f ? e : 0.2f * e;
        if (lane >= 32 && !v1) e = -1e30f;
        float w = __expf(e);
        den_half += w;
        // X gather (coalesced 256B rows)
        int xb0 = (s0 * 64 + pA) * 64 + lane;
        int xb1 = (s1 * 64 + pA) * 64 + lane;
        float xv0[4], xv1[4];
        #pragma unroll
        for (int q = 0; q < 4; ++q) xv0[q] = X[xb0 + q * 64];
        #pragma unroll
        for (int q = 0; q < 4; ++q) xv1[q] = X[xb1 + q * 64];
        #pragma unroll
        for (int q = 0; q < 4; ++q) {
            #pragma unroll
            for (int h = 0; h < 8; ++h) {
                float w0 = rdlane(w, q * 8 + h);
                float w1 = rdlane(w, 32 + q * 8 + h);
                agg[q][h] = fmaf(w0, xv0[q], agg[q][h]);
                agg[q][h] = fmaf(w1, xv1[q], agg[q][h]);
            }
        }
    }
    // combine den halves: lane c and c+32 both end with full den for c
    float den = den_half + __shfl(den_half, lane ^ 32);
    float inv = deg ? 1.f / den : 0.f;

    // scale + pack to bf16 hi/lo planes
    #pragma unroll
    for (int q = 0; q < 4; ++q) {
        int pl = wv * 4 + q;
        #pragma unroll
        for (int h = 0; h < 8; ++h) {
            float iv = rdlane(inv, q * 8 + h);
            accP[h][pl][lane] = packbf(agg[q][h] * iv);
        }
    }
    __syncthreads();

    // MFMA transform: wave wv handles heads 2wv, 2wv+1 (r6-verified layout)
    int m16 = lane & 15, g = lane >> 4;
    #pragma unroll
    for (int hh = 0; hh < 2; ++hh) {
        int h = wv * 2 + hh;
        bf16x8 a_hi[2], a_lo[2];
        #pragma unroll
        for (int ks = 0; ks < 2; ++ks) {
            const unsigned* ap = &accP[h][m16][ks * 32 + g * 8];
            uint4 q0 = *(const uint4*)ap;
            uint4 q1 = *(const uint4*)(ap + 4);
            a_hi[ks][0] = (short)(q0.x & 0xffffu); a_lo[ks][0] = (short)(q0.x >> 16);
            a_hi[ks][1] = (short)(q0.y & 0xffffu); a_lo[ks][1] = (short)(q0.y >> 16);
            a_hi[ks][2] = (short)(q0.z & 0xffffu); a_lo[ks][2] = (short)(q0.z >> 16);
            a_hi[ks][3] = (short)(q0.w & 0xffffu); a_lo[ks][3] = (short)(q0.w >> 16);
            a_hi[ks][4] = (short)(q1.x & 0xffffu); a_lo[ks][4] = (short)(q1.x >> 16);
            a_hi[ks][5] = (short)(q1.y & 0xffffu); a_lo[ks][5] = (short)(q1.y >> 16);
            a_hi[ks][6] = (short)(q1.z & 0xffffu); a_lo[ks][6] = (short)(q1.z >> 16);
            a_hi[ks][7] = (short)(q1.w & 0xffffu); a_lo[ks][7] = (short)(q1.w >> 16);
        }
        #pragma unroll
        for (int nt = 0; nt < 2; ++nt) {
            f32x4 D = {0.f, 0.f, 0.f, 0.f};
            #pragma unroll
            for (int ks = 0; ks < 2; ++ks) {
                const unsigned* bp = &wfrag[(size_t)(((h * 2 + nt) * 2 + ks) * 64 + lane) * 8];
                uint4 w0 = *(const uint4*)bp;
                uint4 w1 = *(const uint4*)(bp + 4);
                bf16x8 b_hi, b_lo;
                b_hi[0] = (short)(w0.x & 0xffffu); b_lo[0] = (short)(w0.x >> 16);
                b_hi[1] = (short)(w0.y & 0xffffu); b_lo[1] = (short)(w0.y >> 16);
                b_hi[2] = (short)(w0.z & 0xffffu); b_lo[2] = (short)(w0.z >> 16);
                b_hi[3] = (short)(w0.w & 0xffffu); b_lo[3] = (short)(w0.w >> 16);
                b_hi[4] = (short)(w1.x & 0xffffu); b_lo[4] = (short)(w1.x >> 16);
                b_hi[5] = (short)(w1.y & 0xffffu); b_lo[5] = (short)(w1.y >> 16);
                b_hi[6] = (short)(w1.z & 0xffffu); b_lo[6] = (short)(w1.z >> 16);
                b_hi[7] = (short)(w1.w & 0xffffu); b_lo[7] = (short)(w1.w >> 16);
                D = __builtin_amdgcn_mfma_f32_16x16x32_bf16(a_hi[ks], b_hi, D, 0, 0, 0);
                D = __builtin_amdgcn_mfma_f32_16x16x32_bf16(a_hi[ks], b_lo, D, 0, 0, 0);
                D = __builtin_amdgcn_mfma_f32_16x16x32_bf16(a_lo[ks], b_hi, D, 0, 0, 0);
            }
            float bv = bias[h * 32 + nt * 16 + m16];
            size_t ob = ((size_t)(n * 64) + p0 + g * 4) * 256 + h * 32 + nt * 16 + m16;
            out[ob]       = D[0] + bv;
            out[ob + 256] = D[1] + bv;
            out[ob + 512] = D[2] + bv;
            out[ob + 768] = D[3] + bv;
        }
    }
}

// ---------------- launch ----------------

extern "C" void kernel_launch(void* const* d_in, const int* in_sizes, int n_in,
                              void* d_out, int out_size, void* d_ws, size_t ws_size,
                              hipStream_t stream) {
    const float* node = (const float*)d_in[0];
    const int* src = (const int*)d_in[1];
    const int* dst = (const int*)d_in[2];
    const float* W1 = (const float*)d_in[3];
    const float* al1 = (const float*)d_in[4];
    const float* ar1 = (const float*)d_in[5];
    const float* b1 = (const float*)d_in[6];
    const float* W2 = (const float*)d_in[7];
    const float* al2 = (const float*)d_in[8];
    const float* ar2 = (const float*)d_in[9];
    const float* b2 = (const float*)d_in[10];
    const float* W3 = (const float*)d_in[11];
    const float* al3 = (const float*)d_in[12];
    const float* ar3 = (const float*)d_in[13];
    const float* b3 = (const float*)d_in[14];
    float* out = (float*)d_out;

    char* ws = (char*)d_ws;
    size_t off = 0;
    auto alloc = [&](size_t nb) -> char* {
        char* q = ws + off;
        off += (nb + 255) & ~(size_t)255;
        return q;
    };
    int* counts   = (int*)alloc((N_NODES + 1) * sizeof(int));
    int* cursor   = (int*)alloc(N_NODES * sizeof(int));
    int* row_ptr  = (int*)alloc((N_NODES + 1) * sizeof(int));
    int* tmp_eid  = (int*)alloc(N_EDGES * sizeof(int));
    int* csr_src  = (int*)alloc(N_EDGES * sizeof(int));
    float* feat1  = (float*)alloc((size_t)N_NODES * 8 * 64 * 4);
    float* el1    = (float*)alloc((size_t)N_NODES * 8 * 4);
    float* er1    = (float*)alloc((size_t)N_NODES * 8 * 4);
    float* h1     = (float*)alloc((size_t)N_NODES * 8 * 64 * 4);
    float* aleff2 = (float*)alloc(8 * 64 * 4);
    float* areff2 = (float*)alloc(8 * 64 * 4);
    float* el2    = (float*)alloc((size_t)N_NODES * 8 * 8 * 4);
    float* er2    = (float*)alloc((size_t)N_NODES * 8 * 8 * 4);
    float* h2     = (float*)alloc((size_t)N_NODES * 64 * 64 * 4);
    float* aleff3 = (float*)alloc(8 * 64 * 4);
    float* areff3 = (float*)alloc(8 * 64 * 4);
    float* el3    = (float*)alloc((size_t)N_NODES * 64 * 8 * 4);
    float* er3    = (float*)alloc((size_t)N_NODES * 64 * 8 * 4);
    float* W4t2   = (float*)alloc((size_t)16 * 512 * 4 * 4);
    unsigned* wfrag3 = (unsigned*)alloc((size_t)16384 * 4);

    const int PREP_T = 1536 + 1536 + 1024 + 1024 + 16 * 512 * 4 + 16384;
    prep_kernel<<<(PREP_T + 255) / 256, 256, 0, stream>>>(
        W2, al2, ar2, W3, al3, ar3, aleff2, areff2, aleff3, areff3, W4t2, wfrag3,
        counts, cursor);

    hist_kernel<<<(N_EDGES + 255) / 256, 256, 0, stream>>>(dst, counts);
    scan_kernel<<<1, 256, 0, stream>>>(counts, row_ptr);
    scatter_kernel<<<(N_EDGES + 255) / 256, 256, 0, stream>>>(dst, row_ptr, cursor, tmp_eid);
    sort_csr_kernel<<<(N_NODES * 64 + 255) / 256, 256, 0, stream>>>(row_ptr, tmp_eid, src, csr_src);

    // ---- layer 1 ----
    dim3 g1((512 + GN - 1) / GN, (N_NODES + GM - 1) / GM);
    gemm_f32<<<g1, 256, 0, stream>>>(node, W1, feat1, N_NODES, 512, IN_FEAT);
    elr_feat_kernel<<<(N_NODES * 8 + 255) / 256, 256, 0, stream>>>(feat1, al1, ar1, el1, er1, N_NODES * 8);
    agg_l1<<<N_NODES, 256, 0, stream>>>(feat1, el1, er1, b1, row_ptr, csr_src, h1);

    // ---- layer 2 ----
    elr_row_kernel<<<(N_NODES * 8 + 255) / 256, 256, 0, stream>>>(h1, aleff2, areff2, el2, er2, N_NODES * 8);
    agg_fused4<64, true, 8><<<N_NODES, 256, 0, stream>>>(h1, el2, er2, W4t2, b2, row_ptr, csr_src, h2);

    // ---- layer 3 ----
    elr_row_kernel<<<(N_NODES * 64 + 255) / 256, 256, 0, stream>>>(h2, aleff3, areff3, el3, er3, N_NODES * 64);
    agg_mfma5<<<N_NODES * 4, 256, 0, stream>>>(h2, el3, er3, wfrag3, b3, row_ptr, csr_src, out);
}

// Round 9
// 176.329 us; speedup vs baseline: 1.4156x; 1.0061x over previous
//
#include <hip/hip_runtime.h>
#include <math.h>

#define N_NODES 1500
#define N_EDGES 12000
#define IN_FEAT 512
#define HIDDEN 64
#define OUT_FEAT 32
#define HEADS 8

typedef short bf16x8 __attribute__((ext_vector_type(8)));
typedef float f32x4 __attribute__((ext_vector_type(4)));

__device__ __forceinline__ unsigned short f2bf(float f) {
    unsigned u = __float_as_uint(f);
    u += 0x7fff + ((u >> 16) & 1);   // RNE
    return (unsigned short)(u >> 16);
}
__device__ __forceinline__ float bf2f(unsigned short b) {
    return __uint_as_float(((unsigned)b) << 16);
}
__device__ __forceinline__ unsigned packbf(float a) {
    unsigned short hi = f2bf(a);
    unsigned short lo = f2bf(a - bf2f(hi));
    return (unsigned)hi | ((unsigned)lo << 16);
}
__device__ __forceinline__ float rdlanef(float v, int c) {
    return __uint_as_float(__builtin_amdgcn_readlane(__float_as_uint(v), c));
}

// ---------------- fused prep: zeros + att-eff vectors + W2 reshuffle + W3 hi/lo frags ----
// W4t2[(kg*512 + c)*4 + j] = W2[(kg*4+j)*512 + c]
// wfhi/wflo: [(h*2+nt)*2+ks][lane][4 words]; word j2 = bf16(k=base+2j2) | bf16(k=base+2j2+1)<<16
// (exact bf16x8 memory layout: element j of the MFMA B-fragment, k = ks*32+(l>>4)*8+j)

__global__ void prep_kernel(const float* __restrict__ W2, const float* __restrict__ al2,
                            const float* __restrict__ ar2,
                            const float* __restrict__ W3, const float* __restrict__ al3,
                            const float* __restrict__ ar3,
                            float* __restrict__ aleff2, float* __restrict__ areff2,
                            float* __restrict__ aleff3, float* __restrict__ areff3,
                            float* __restrict__ W4t2,
                            unsigned* __restrict__ wfhi, unsigned* __restrict__ wflo,
                            int* __restrict__ counts, int* __restrict__ cursor) {
    int i = blockIdx.x * blockDim.x + threadIdx.x;
    if (i < 1536) {
        if (i < N_NODES + 1) counts[i] = 0;
        return;
    }
    i -= 1536;
    if (i < 1536) {
        if (i < N_NODES) cursor[i] = 0;
        return;
    }
    i -= 1536;
    if (i < 1024) {  // aleff2 / areff2
        int lr = i >> 9; i &= 511;
        int h = i >> 6, k = i & 63;
        const float* a = lr ? ar2 : al2;
        float s = 0.f;
        for (int f = 0; f < 64; ++f)
            s = fmaf(W2[(size_t)k * 512 + h * 64 + f], a[h * 64 + f], s);
        (lr ? areff2 : aleff2)[h * 64 + k] = s;
        return;
    }
    i -= 1024;
    if (i < 1024) {  // aleff3 / areff3
        int lr = i >> 9; i &= 511;
        int h = i >> 6, k = i & 63;
        const float* a = lr ? ar3 : al3;
        float s = 0.f;
        for (int f = 0; f < 32; ++f)
            s = fmaf(W3[(size_t)k * 256 + h * 32 + f], a[h * 32 + f], s);
        (lr ? areff3 : aleff3)[h * 64 + k] = s;
        return;
    }
    i -= 1024;
    if (i < 16 * 512 * 4) {  // W4t2
        int kg = i >> 11, rem = i & 2047;
        int c = rem >> 2, j = rem & 3;
        W4t2[i] = W2[(size_t)(kg * 4 + j) * 512 + c];
        return;
    }
    i -= 16 * 512 * 4;
    if (i < 16384) {  // wfhi / wflo
        int plane = i >> 13;
        int rem = i & 8191;
        int j2 = rem & 3, l = (rem >> 2) & 63;
        int ks = (rem >> 8) & 1, nt = (rem >> 9) & 1, h = (rem >> 10) & 7;
        int col = h * 32 + nt * 16 + (l & 15);
        int kb = ks * 32 + (l >> 4) * 8 + 2 * j2;
        unsigned parts[2];
        #pragma unroll
        for (int q = 0; q < 2; ++q) {
            float w = W3[(size_t)(kb + q) * 256 + col];
            unsigned short hi = f2bf(w);
            parts[q] = plane ? (unsigned)f2bf(w - bf2f(hi)) : (unsigned)hi;
        }
        unsigned word = parts[0] | (parts[1] << 16);
        (plane ? wflo : wfhi)[rem] = word;
    }
}

__global__ void hist_kernel(const int* __restrict__ dst, int* __restrict__ counts) {
    int e = blockIdx.x * blockDim.x + threadIdx.x;
    if (e < N_EDGES) atomicAdd(&counts[dst[e]], 1);
}

__global__ void scan_kernel(const int* __restrict__ counts, int* __restrict__ row_ptr) {
    __shared__ int part[256];
    int t = threadIdx.x;
    const int CH = (N_NODES + 255) / 256;
    int base = t * CH;
    int loc[8];
    int s = 0;
    for (int i = 0; i < CH; ++i) {
        int idx = base + i;
        int v = (idx < N_NODES) ? counts[idx] : 0;
        loc[i] = s;
        s += v;
    }
    part[t] = s;
    __syncthreads();
    if (t == 0) {
        int a = 0;
        for (int i = 0; i < 256; ++i) { int v = part[i]; part[i] = a; a += v; }
        row_ptr[N_NODES] = a;
    }
    __syncthreads();
    int p0 = part[t];
    for (int i = 0; i < CH; ++i) {
        int idx = base + i;
        if (idx < N_NODES) row_ptr[idx] = p0 + loc[i];
    }
}

__global__ void scatter_kernel(const int* __restrict__ dst, const int* __restrict__ row_ptr,
                               int* __restrict__ cursor, int* __restrict__ tmp_eid) {
    int e = blockIdx.x * blockDim.x + threadIdx.x;
    if (e < N_EDGES) {
        int d = dst[e];
        int pos = row_ptr[d] + atomicAdd(&cursor[d], 1);
        tmp_eid[pos] = e;
    }
}

// per-node sort by edge id -> deterministic stable order
__global__ void sort_csr_kernel(const int* __restrict__ row_ptr, const int* __restrict__ tmp_eid,
                                const int* __restrict__ src, int* __restrict__ csr_src) {
    int wid = (blockIdx.x * blockDim.x + threadIdx.x) >> 6;
    int lane = threadIdx.x & 63;
    if (wid >= N_NODES) return;
    int r0 = row_ptr[wid], deg = row_ptr[wid + 1] - r0;
    for (int base = 0; base < deg; base += 64) {
        int i = base + lane;
        int my = (i < deg) ? tmp_eid[r0 + i] : 0x7fffffff;
        int rank = 0;
        for (int b2 = 0; b2 < deg; b2 += 64) {
            int other = (b2 + lane < deg) ? tmp_eid[r0 + b2 + lane] : 0x7fffffff;
            int cnt2 = min(deg - b2, 64);
            for (int j = 0; j < cnt2; ++j) {
                int oj = __shfl(other, j);
                rank += (oj < my) ? 1 : 0;
            }
        }
        if (i < deg) csr_src[r0 + rank] = src[my];
    }
}

// ---------------- f32 tiled GEMM (layer 1): 32x32 tiles (752 blocks) ----------

#define GM 32
#define GN 32
#define GK 32

__global__ __launch_bounds__(256) void gemm_f32(const float* __restrict__ A,
                                                const float* __restrict__ B,
                                                float* __restrict__ C,
                                                int M, int N, int K) {
    __shared__ float As[GK][GM + 2];
    __shared__ float Bs[GK][GN + 2];
    int t = threadIdx.x;
    int col0 = blockIdx.x * GN, row0 = blockIdx.y * GM;
    int tx = t & 15, ty = t >> 4;
    int am = t >> 3, ak = (t & 7) * 4;
    int bk = t >> 3, bn = (t & 7) * 4;
    float acc[2][2] = {};
    for (int k0 = 0; k0 < K; k0 += GK) {
        int gr = row0 + am;
        float4 av = (gr < M) ? *(const float4*)&A[(size_t)gr * K + k0 + ak]
                             : make_float4(0.f, 0.f, 0.f, 0.f);
        float4 bv = *(const float4*)&B[(size_t)(k0 + bk) * N + col0 + bn];
        __syncthreads();
        As[ak + 0][am] = av.x; As[ak + 1][am] = av.y;
        As[ak + 2][am] = av.z; As[ak + 3][am] = av.w;
        *(float4*)&Bs[bk][bn] = bv;
        __syncthreads();
        #pragma unroll
        for (int kk = 0; kk < GK; ++kk) {
            float2 a2 = *(const float2*)&As[kk][ty * 2];
            float2 b2 = *(const float2*)&Bs[kk][tx * 2];
            acc[0][0] = fmaf(a2.x, b2.x, acc[0][0]);
            acc[0][1] = fmaf(a2.x, b2.y, acc[0][1]);
            acc[1][0] = fmaf(a2.y, b2.x, acc[1][0]);
            acc[1][1] = fmaf(a2.y, b2.y, acc[1][1]);
        }
    }
    #pragma unroll
    for (int i = 0; i < 2; ++i) {
        int gr = row0 + ty * 2 + i;
        if (gr < M) {
            float2 v = make_float2(acc[i][0], acc[i][1]);
            *(float2*)&C[(size_t)gr * N + col0 + tx * 2] = v;
        }
    }
}

// ---------------- el/er kernels ----------------

__global__ void elr_feat_kernel(const float* __restrict__ feat, const float* __restrict__ al,
                                const float* __restrict__ ar, float* __restrict__ el,
                                float* __restrict__ er, int RH) {
    int idx = blockIdx.x * blockDim.x + threadIdx.x;
    if (idx >= RH) return;
    int h = idx & (HEADS - 1);
    const float* fp = feat + (size_t)idx * HIDDEN;
    float sl = 0.f, sr = 0.f;
    for (int f = 0; f < HIDDEN; ++f) {
        float v = fp[f];
        sl = fmaf(v, al[h * HIDDEN + f], sl);
        sr = fmaf(v, ar[h * HIDDEN + f], sr);
    }
    el[idx] = sl;
    er[idx] = sr;
}

__global__ void elr_row_kernel(const float* __restrict__ X, const float* __restrict__ alv,
                               const float* __restrict__ arv, float* __restrict__ el,
                               float* __restrict__ er, int R) {
    int r = blockIdx.x * blockDim.x + threadIdx.x;
    if (r >= R) return;
    const float4* x4 = (const float4*)(X + (size_t)r * 64);
    float sl[8] = {}, sr[8] = {};
    for (int kg = 0; kg < 16; ++kg) {
        float4 xv = x4[kg];
        #pragma unroll
        for (int h = 0; h < 8; ++h) {
            float4 a = *(const float4*)&alv[h * 64 + kg * 4];
            float4 b = *(const float4*)&arv[h * 64 + kg * 4];
            sl[h] = fmaf(xv.x, a.x, fmaf(xv.y, a.y, fmaf(xv.z, a.z, fmaf(xv.w, a.w, sl[h]))));
            sr[h] = fmaf(xv.x, b.x, fmaf(xv.y, b.y, fmaf(xv.z, b.z, fmaf(xv.w, b.w, sr[h]))));
        }
    }
    float* elp = el + (size_t)r * 8;
    float* erp = er + (size_t)r * 8;
    #pragma unroll
    for (int h = 0; h < 8; ++h) { elp[h] = sl[h]; erp[h] = sr[h]; }
}

__device__ __forceinline__ float gelu_exact(float v) {
    return 0.5f * v * (1.0f + erff(v * 0.70710678118654752440f));
}

// ---------------- layer-1 aggregation: wave per (node, head-pair), src in registers ----------
__global__ __launch_bounds__(256) void agg_l1(
    const float* __restrict__ feat, const float* __restrict__ el, const float* __restrict__ er,
    const float* __restrict__ bias, const int* __restrict__ row_ptr,
    const int* __restrict__ csr_src, float* __restrict__ out) {
    int n = blockIdx.x;
    int t = threadIdx.x, wv = t >> 6, lane = t & 63;
    int h0 = 2 * wv;
    int r0 = row_ptr[n], deg = row_ptr[n + 1] - r0;
    float2 erv = *(const float2*)&er[n * 8 + h0];
    float den0 = 0.f, den1 = 0.f, a0 = 0.f, a1 = 0.f;
    for (int c0 = 0; c0 < deg; c0 += 64) {
        int cnt = min(deg - c0, 64);
        int src_r = (lane < cnt) ? csr_src[r0 + c0 + lane] : 0;
        auto do_edge = [&](int s) {
            float2 elv = *(const float2*)&el[s * 8 + h0];
            float x0 = feat[((size_t)s * 8 + h0) * 64 + lane];
            float x1 = feat[((size_t)s * 8 + h0 + 1) * 64 + lane];
            float e0 = elv.x + erv.x; e0 = e0 > 0.f ? e0 : 0.2f * e0;
            float e1 = elv.y + erv.y; e1 = e1 > 0.f ? e1 : 0.2f * e1;
            float w0 = __expf(e0), w1 = __expf(e1);
            den0 += w0; den1 += w1;
            a0 = fmaf(w0, x0, a0);
            a1 = fmaf(w1, x1, a1);
        };
        int i = 0;
        for (; i + 2 <= cnt; i += 2) {
            int s0 = __builtin_amdgcn_readlane(src_r, i);
            int s1 = __builtin_amdgcn_readlane(src_r, i + 1);
            do_edge(s0);
            do_edge(s1);
        }
        if (i < cnt) do_edge(__builtin_amdgcn_readlane(src_r, i));
    }
    float i0 = deg ? 1.f / den0 : 0.f;
    float i1 = deg ? 1.f / den1 : 0.f;
    float v0 = a0 * i0 + bias[h0 * 64 + lane];
    float v1 = a1 * i1 + bias[(h0 + 1) * 64 + lane];
    out[((size_t)n * 8 + h0) * 64 + lane] = gelu_exact(v0);
    out[((size_t)n * 8 + h0 + 1) * 64 + lane] = gelu_exact(v1);
}

// ---------------- layer 2: LDS-staged weights + register-blocked transform ----------------
template <int FOUT, bool GELU, int P>
__global__ __launch_bounds__(256, 4) void agg_fused4(
    const float* __restrict__ X,
    const float* __restrict__ el, const float* __restrict__ er,
    const float* __restrict__ W4t,
    const float* __restrict__ bias,
    const int* __restrict__ row_ptr, const int* __restrict__ csr_src,
    float* __restrict__ out)
{
    constexpr int TOT = 8 * FOUT;
    constexpr int KSPLIT = 2;
    constexpr int KGPT = 8;
    constexpr int FELEM = (FOUT == 32) ? 2 : 4;
    constexpr int FQn = FOUT / FELEM;
    constexpr int TPK = 8 * FQn;
    constexpr int FQ4 = FOUT / 4;
    constexpr int PTS = FOUT + 4;
    constexpr int WPFL = (KSPLIT * 64 * PTS > 64 * 64) ? KSPLIT * 64 * PTS : 64 * 64;
    constexpr int GRPS = P / 8;
    constexpr int CHUNK = 64;

    int nb = blockIdx.x;
    int n = nb / GRPS, pg = nb - n * GRPS;
    int p0 = pg * 8;
    int r0 = row_ptr[n], deg = row_ptr[n + 1] - r0;
    int t = threadIdx.x, wv = t >> 6, lane = t & 63;

    __shared__ float inv_s[64];
    __shared__ float acc_s[8][8][68];
    __shared__ float wp_lds[WPFL];

    float agg0[8], agg1[8];
    #pragma unroll
    for (int h = 0; h < 8; ++h) { agg0[h] = 0.f; agg1[h] = 0.f; }
    float den = 0.f;

    int elbase_n = (n * P + p0) * 8;
    int pA = p0 + wv * 2;
    float erv_t = er[elbase_n + lane];   // plh for this thread is (t & 63) in the w-phase

    for (int c0 = 0; c0 < deg; c0 += CHUNK) {
        int cnt = min(deg - c0, CHUNK);
        int src_r = (lane < cnt) ? csr_src[r0 + c0 + lane] : 0;
        __syncthreads();
        for (int j = t; j < cnt * 64; j += 256) {
            int i = j >> 6;
            int s = __builtin_amdgcn_readlane(src_r, i);
            float e = el[(s * P + p0) * 8 + lane] + erv_t;
            e = e > 0.f ? e : 0.2f * e;
            wp_lds[i * 64 + lane] = __expf(e);
        }
        __syncthreads();
        if (t < 64) {
            for (int i = 0; i < cnt; ++i) den += wp_lds[i * 64 + t];
        }
        auto edge_fma = [&](int i) {
            int s = __builtin_amdgcn_readlane(src_r, i);
            const float* wp = &wp_lds[i * 64 + wv * 16];
            float4 w0 = *(const float4*)wp;
            float4 w1 = *(const float4*)(wp + 4);
            float4 w2 = *(const float4*)(wp + 8);
            float4 w3 = *(const float4*)(wp + 12);
            int xb = (s * P + pA) * 64 + lane;
            float xv0 = X[xb];
            float xv1 = X[xb + 64];
            agg0[0] = fmaf(w0.x, xv0, agg0[0]);
            agg0[1] = fmaf(w0.y, xv0, agg0[1]);
            agg0[2] = fmaf(w0.z, xv0, agg0[2]);
            agg0[3] = fmaf(w0.w, xv0, agg0[3]);
            agg0[4] = fmaf(w1.x, xv0, agg0[4]);
            agg0[5] = fmaf(w1.y, xv0, agg0[5]);
            agg0[6] = fmaf(w1.z, xv0, agg0[6]);
            agg0[7] = fmaf(w1.w, xv0, agg0[7]);
            agg1[0] = fmaf(w2.x, xv1, agg1[0]);
            agg1[1] = fmaf(w2.y, xv1, agg1[1]);
            agg1[2] = fmaf(w2.z, xv1, agg1[2]);
            agg1[3] = fmaf(w2.w, xv1, agg1[3]);
            agg1[4] = fmaf(w3.x, xv1, agg1[4]);
            agg1[5] = fmaf(w3.y, xv1, agg1[5]);
            agg1[6] = fmaf(w3.z, xv1, agg1[6]);
            agg1[7] = fmaf(w3.w, xv1, agg1[7]);
        };
        int i = 0;
        for (; i + 2 <= cnt; i += 2) { edge_fma(i); edge_fma(i + 1); }
        if (i < cnt) edge_fma(i);
    }
    if (t < 64) inv_s[t] = deg ? 1.f / den : 0.f;
    __syncthreads();
    {
        int pl0 = wv * 2;
        #pragma unroll
        for (int h = 0; h < 8; ++h) {
            acc_s[pl0][h][lane] = agg0[h] * inv_s[pl0 * 8 + h];
            acc_s[pl0 + 1][h][lane] = agg1[h] * inv_s[pl0 * 8 + 8 + h];
        }
    }
    __syncthreads();

    {
        int kq = t / TPK;
        int rem = t - kq * TPK;
        int h = rem / FQn;
        int ft = rem - h * FQn;
        int f0 = ft * FELEM;
        float part[8][FELEM];
        #pragma unroll
        for (int pl = 0; pl < 8; ++pl)
            #pragma unroll
            for (int j = 0; j < FELEM; ++j) part[pl][j] = 0.f;
        #pragma unroll
        for (int kk = 0; kk < KGPT; ++kk) {
            int kg = kq * KGPT + kk;
            float4 wr[FELEM];
            #pragma unroll
            for (int j = 0; j < FELEM; ++j)
                wr[j] = *(const float4*)&W4t[(size_t)(kg * TOT + h * FOUT + f0 + j) * 4];
            #pragma unroll
            for (int pl = 0; pl < 8; ++pl) {
                float4 a4 = *(const float4*)&acc_s[pl][h][kg * 4];
                #pragma unroll
                for (int j = 0; j < FELEM; ++j)
                    part[pl][j] = fmaf(a4.x, wr[j].x, fmaf(a4.y, wr[j].y,
                                  fmaf(a4.z, wr[j].z, fmaf(a4.w, wr[j].w, part[pl][j]))));
            }
        }
        #pragma unroll
        for (int pl = 0; pl < 8; ++pl) {
            float* dstp = &wp_lds[((kq * 8 + pl) * 8 + h) * PTS + f0];
            if (FELEM == 4)
                *(float4*)dstp = make_float4(part[pl][0], part[pl][1], part[pl][2], part[pl][3]);
            else
                *(float2*)dstp = make_float2(part[pl][0], part[pl][1]);
        }
    }
    __syncthreads();

    {
        constexpr int NQ = 2 * TOT;
        for (int q = t; q < NQ; q += 256) {
            int pl = q / (TOT / 4);
            int rem = q - pl * (TOT / 4);
            int h = rem / FQ4, fq = rem - h * FQ4;
            int f0 = fq * 4;
            float4 acc4 = *(const float4*)&wp_lds[((0 * 8 + pl) * 8 + h) * PTS + f0];
            #pragma unroll
            for (int kq = 1; kq < KSPLIT; ++kq) {
                float4 pv = *(const float4*)&wp_lds[((kq * 8 + pl) * 8 + h) * PTS + f0];
                acc4.x += pv.x; acc4.y += pv.y; acc4.z += pv.z; acc4.w += pv.w;
            }
            float4 b4 = *(const float4*)&bias[h * FOUT + f0];
            acc4.x += b4.x; acc4.y += b4.y; acc4.z += b4.z; acc4.w += b4.w;
            if (GELU) {
                acc4.x = gelu_exact(acc4.x); acc4.y = gelu_exact(acc4.y);
                acc4.z = gelu_exact(acc4.z); acc4.w = gelu_exact(acc4.w);
            }
            *(float4*)&out[(size_t)(n * P + p0 + pl) * TOT + h * FOUT + f0] = acc4;
        }
    }
}

// ---------------- layer 3: register-src aggregation + MFMA transform ----------------
// Block = (node, 16-p group), 6000 blocks, LDS = accP only -> 4 blocks/CU.
// src ids live in registers (readlane); 4 edges in flight per iteration.
// XCD partition: same pg on same XCD pair (X slice ~6.1MB ~ 2x L2).
__global__ __launch_bounds__(256, 4) void agg_mfma5(
    const float* __restrict__ X,        // h2 [N*64, 64]
    const float* __restrict__ el, const float* __restrict__ er,  // [N*64, 8]
    const unsigned* __restrict__ wfhi, const unsigned* __restrict__ wflo,
    const float* __restrict__ bias,     // [256]
    const int* __restrict__ row_ptr, const int* __restrict__ csr_src,
    float* __restrict__ out)            // [N*64, 256]
{
    int b = blockIdx.x;                  // 6000 = 4 pg * 1500 n
    int w = (b & 7) * 750 + (b >> 3);    // bijective: XCD x gets w in [x*750, x*750+750)
    int pg = w / N_NODES, n = w - pg * N_NODES;
    int p0 = pg * 16;
    int r0 = row_ptr[n], deg = row_ptr[n + 1] - r0;
    int t = threadIdx.x, wv = t >> 6, lane = t & 63;
    int pA = p0 + wv * 4;

    __shared__ unsigned accP[8][16][68];   // [h][pl][k] packed bf16 hi|lo

    int c = lane & 31;                     // (q,h) = (c>>3, c&7)
    float erv = er[(n * 64 + pA) * 8 + c];

    float agg[4][8];
    #pragma unroll
    for (int q = 0; q < 4; ++q)
        #pragma unroll
        for (int h = 0; h < 8; ++h) agg[q][h] = 0.f;
    float den_half = 0.f;

    for (int c0 = 0; c0 < deg; c0 += 64) {
        int cnt = min(deg - c0, 64);
        int src_r = (lane < cnt) ? csr_src[r0 + c0 + lane] : 0;
        for (int it = 0; it < cnt; it += 4) {
            int i1 = min(it + 1, cnt - 1), i2 = min(it + 2, cnt - 1), i3 = min(it + 3, cnt - 1);
            int s0 = __builtin_amdgcn_readlane(src_r, it);
            int s1 = __builtin_amdgcn_readlane(src_r, i1);
            int s2 = __builtin_amdgcn_readlane(src_r, i2);
            int s3 = __builtin_amdgcn_readlane(src_r, i3);
            bool v1 = it + 1 < cnt, v2 = it + 2 < cnt, v3 = it + 3 < cnt;
            int sA = (lane < 32) ? s0 : s1;
            int sB = (lane < 32) ? s2 : s3;
            float eA = el[(sA * 64 + pA) * 8 + c] + erv;
            float eB = el[(sB * 64 + pA) * 8 + c] + erv;
            eA = eA > 0.f ? eA : 0.2f * eA;
            eB = eB > 0.f ? eB : 0.2f * eB;
            if (lane >= 32 && !v1) eA = -1e30f;
            if (lane < 32 && !v2) eB = -1e30f;
            if (lane >= 32 && !v3) eB = -1e30f;
            float wA = __expf(eA), wB = __expf(eB);
            den_half += wA + wB;
            int xb0 = (s0 * 64 + pA) * 64 + lane;
            int xb1 = (s1 * 64 + pA) * 64 + lane;
            int xb2 = (s2 * 64 + pA) * 64 + lane;
            int xb3 = (s3 * 64 + pA) * 64 + lane;
            float x0[4], x1[4], x2[4], x3[4];
            #pragma unroll
            for (int q = 0; q < 4; ++q) x0[q] = X[xb0 + q * 64];
            #pragma unroll
            for (int q = 0; q < 4; ++q) x1[q] = X[xb1 + q * 64];
            #pragma unroll
            for (int q = 0; q < 4; ++q) x2[q] = X[xb2 + q * 64];
            #pragma unroll
            for (int q = 0; q < 4; ++q) x3[q] = X[xb3 + q * 64];
            #pragma unroll
            for (int q = 0; q < 4; ++q) {
                #pragma unroll
                for (int h = 0; h < 8; ++h) {
                    agg[q][h] = fmaf(rdlanef(wA, q * 8 + h), x0[q], agg[q][h]);
                    agg[q][h] = fmaf(rdlanef(wA, 32 + q * 8 + h), x1[q], agg[q][h]);
                    agg[q][h] = fmaf(rdlanef(wB, q * 8 + h), x2[q], agg[q][h]);
                    agg[q][h] = fmaf(rdlanef(wB, 32 + q * 8 + h), x3[q], agg[q][h]);
                }
            }
        }
    }
    float den = den_half + __shfl(den_half, lane ^ 32);
    float inv = deg ? 1.f / den : 0.f;

    // scale + pack to bf16 hi/lo planes
    #pragma unroll
    for (int q = 0; q < 4; ++q) {
        int pl = wv * 4 + q;
        #pragma unroll
        for (int h = 0; h < 8; ++h) {
            float iv = rdlanef(inv, q * 8 + h);
            accP[h][pl][lane] = packbf(agg[q][h] * iv);
        }
    }
    __syncthreads();

    // MFMA transform: wave wv handles heads 2wv, 2wv+1
    int m16 = lane & 15, g = lane >> 4;
    #pragma unroll
    for (int hh = 0; hh < 2; ++hh) {
        int h = wv * 2 + hh;
        bf16x8 a_hi[2], a_lo[2];
        #pragma unroll
        for (int ks = 0; ks < 2; ++ks) {
            const unsigned* ap = &accP[h][m16][ks * 32 + g * 8];
            uint4 q0 = *(const uint4*)ap;
            uint4 q1 = *(const uint4*)(ap + 4);
            a_hi[ks][0] = (short)(q0.x & 0xffffu); a_lo[ks][0] = (short)(q0.x >> 16);
            a_hi[ks][1] = (short)(q0.y & 0xffffu); a_lo[ks][1] = (short)(q0.y >> 16);
            a_hi[ks][2] = (short)(q0.z & 0xffffu); a_lo[ks][2] = (short)(q0.z >> 16);
            a_hi[ks][3] = (short)(q0.w & 0xffffu); a_lo[ks][3] = (short)(q0.w >> 16);
            a_hi[ks][4] = (short)(q1.x & 0xffffu); a_lo[ks][4] = (short)(q1.x >> 16);
            a_hi[ks][5] = (short)(q1.y & 0xffffu); a_lo[ks][5] = (short)(q1.y >> 16);
            a_hi[ks][6] = (short)(q1.z & 0xffffu); a_lo[ks][6] = (short)(q1.z >> 16);
            a_hi[ks][7] = (short)(q1.w & 0xffffu); a_lo[ks][7] = (short)(q1.w >> 16);
        }
        #pragma unroll
        for (int nt = 0; nt < 2; ++nt) {
            f32x4 D = {0.f, 0.f, 0.f, 0.f};
            #pragma unroll
            for (int ks = 0; ks < 2; ++ks) {
                size_t fb = (size_t)(((h * 2 + nt) * 2 + ks) * 64 + lane) * 4;
                bf16x8 b_hi = *(const bf16x8*)&wfhi[fb];
                bf16x8 b_lo = *(const bf16x8*)&wflo[fb];
                D = __builtin_amdgcn_mfma_f32_16x16x32_bf16(a_hi[ks], b_hi, D, 0, 0, 0);
                D = __builtin_amdgcn_mfma_f32_16x16x32_bf16(a_hi[ks], b_lo, D, 0, 0, 0);
                D = __builtin_amdgcn_mfma_f32_16x16x32_bf16(a_lo[ks], b_hi, D, 0, 0, 0);
            }
            float bv = bias[h * 32 + nt * 16 + m16];
            size_t ob = ((size_t)(n * 64) + p0 + g * 4) * 256 + h * 32 + nt * 16 + m16;
            out[ob]       = D[0] + bv;
            out[ob + 256] = D[1] + bv;
            out[ob + 512] = D[2] + bv;
            out[ob + 768] = D[3] + bv;
        }
    }
}

// ---------------- launch ----------------

extern "C" void kernel_launch(void* const* d_in, const int* in_sizes, int n_in,
                              void* d_out, int out_size, void* d_ws, size_t ws_size,
                              hipStream_t stream) {
    const float* node = (const float*)d_in[0];
    const int* src = (const int*)d_in[1];
    const int* dst = (const int*)d_in[2];
    const float* W1 = (const float*)d_in[3];
    const float* al1 = (const float*)d_in[4];
    const float* ar1 = (const float*)d_in[5];
    const float* b1 = (const float*)d_in[6];
    const float* W2 = (const float*)d_in[7];
    const float* al2 = (const float*)d_in[8];
    const float* ar2 = (const float*)d_in[9];
    const float* b2 = (const float*)d_in[10];
    const float* W3 = (const float*)d_in[11];
    const float* al3 = (const float*)d_in[12];
    const float* ar3 = (const float*)d_in[13];
    const float* b3 = (const float*)d_in[14];
    float* out = (float*)d_out;

    char* ws = (char*)d_ws;
    size_t off = 0;
    auto alloc = [&](size_t nb) -> char* {
        char* q = ws + off;
        off += (nb + 255) & ~(size_t)255;
        return q;
    };
    int* counts   = (int*)alloc((N_NODES + 1) * sizeof(int));
    int* cursor   = (int*)alloc(N_NODES * sizeof(int));
    int* row_ptr  = (int*)alloc((N_NODES + 1) * sizeof(int));
    int* tmp_eid  = (int*)alloc(N_EDGES * sizeof(int));
    int* csr_src  = (int*)alloc(N_EDGES * sizeof(int));
    float* feat1  = (float*)alloc((size_t)N_NODES * 8 * 64 * 4);
    float* el1    = (float*)alloc((size_t)N_NODES * 8 * 4);
    float* er1    = (float*)alloc((size_t)N_NODES * 8 * 4);
    float* h1     = (float*)alloc((size_t)N_NODES * 8 * 64 * 4);
    float* aleff2 = (float*)alloc(8 * 64 * 4);
    float* areff2 = (float*)alloc(8 * 64 * 4);
    float* el2    = (float*)alloc((size_t)N_NODES * 8 * 8 * 4);
    float* er2    = (float*)alloc((size_t)N_NODES * 8 * 8 * 4);
    float* h2     = (float*)alloc((size_t)N_NODES * 64 * 64 * 4);
    float* aleff3 = (float*)alloc(8 * 64 * 4);
    float* areff3 = (float*)alloc(8 * 64 * 4);
    float* el3    = (float*)alloc((size_t)N_NODES * 64 * 8 * 4);
    float* er3    = (float*)alloc((size_t)N_NODES * 64 * 8 * 4);
    float* W4t2   = (float*)alloc((size_t)16 * 512 * 4 * 4);
    unsigned* wfhi = (unsigned*)alloc((size_t)8192 * 4);
    unsigned* wflo = (unsigned*)alloc((size_t)8192 * 4);

    const int PREP_T = 1536 + 1536 + 1024 + 1024 + 16 * 512 * 4 + 16384;
    prep_kernel<<<(PREP_T + 255) / 256, 256, 0, stream>>>(
        W2, al2, ar2, W3, al3, ar3, aleff2, areff2, aleff3, areff3, W4t2, wfhi, wflo,
        counts, cursor);

    hist_kernel<<<(N_EDGES + 255) / 256, 256, 0, stream>>>(dst, counts);
    scan_kernel<<<1, 256, 0, stream>>>(counts, row_ptr);
    scatter_kernel<<<(N_EDGES + 255) / 256, 256, 0, stream>>>(dst, row_ptr, cursor, tmp_eid);
    sort_csr_kernel<<<(N_NODES * 64 + 255) / 256, 256, 0, stream>>>(row_ptr, tmp_eid, src, csr_src);

    // ---- layer 1 ----
    dim3 g1((512 + GN - 1) / GN, (N_NODES + GM - 1) / GM);
    gemm_f32<<<g1, 256, 0, stream>>>(node, W1, feat1, N_NODES, 512, IN_FEAT);
    elr_feat_kernel<<<(N_NODES * 8 + 255) / 256, 256, 0, stream>>>(feat1, al1, ar1, el1, er1, N_NODES * 8);
    agg_l1<<<N_NODES, 256, 0, stream>>>(feat1, el1, er1, b1, row_ptr, csr_src, h1);

    // ---- layer 2 ----
    elr_row_kernel<<<(N_NODES * 8 + 255) / 256, 256, 0, stream>>>(h1, aleff2, areff2, el2, er2, N_NODES * 8);
    agg_fused4<64, true, 8><<<N_NODES, 256, 0, stream>>>(h1, el2, er2, W4t2, b2, row_ptr, csr_src, h2);

    // ---- layer 3 ----
    elr_row_kernel<<<(N_NODES * 64 + 255) / 256, 256, 0, stream>>>(h2, aleff3, areff3, el3, er3, N_NODES * 64);
    agg_mfma5<<<N_NODES * 4, 256, 0, stream>>>(h2, el3, er3, wfhi, wflo, b3, row_ptr, csr_src, out);
}

// Round 10
// 168.737 us; speedup vs baseline: 1.4793x; 1.0450x over previous
//
#include <hip/hip_runtime.h>
#include <math.h>

#define N_NODES 1500
#define N_EDGES 12000
#define IN_FEAT 512
#define HIDDEN 64
#define OUT_FEAT 32
#define HEADS 8

typedef short bf16x8 __attribute__((ext_vector_type(8)));
typedef float f32x4 __attribute__((ext_vector_type(4)));

__device__ __forceinline__ unsigned short f2bf(float f) {
    unsigned u = __float_as_uint(f);
    u += 0x7fff + ((u >> 16) & 1);   // RNE
    return (unsigned short)(u >> 16);
}
__device__ __forceinline__ float bf2f(unsigned short b) {
    return __uint_as_float(((unsigned)b) << 16);
}
__device__ __forceinline__ unsigned packbf(float a) {
    unsigned short hi = f2bf(a);
    unsigned short lo = f2bf(a - bf2f(hi));
    return (unsigned)hi | ((unsigned)lo << 16);
}
__device__ __forceinline__ float rdlanef(float v, int c) {
    return __uint_as_float(__builtin_amdgcn_readlane(__float_as_uint(v), c));
}

// ---------------- fused prep: zeros + att-eff vectors + W2 reshuffle + W3 hi/lo frags ----
// W4t2[(kg*512 + c)*4 + j] = W2[(kg*4+j)*512 + c]
// wfhi/wflo: [(h*2+nt)*2+ks][lane][4 words]; word j2 = bf16(k=base+2j2) | bf16(k=base+2j2+1)<<16

__global__ void prep_kernel(const float* __restrict__ W2, const float* __restrict__ al2,
                            const float* __restrict__ ar2,
                            const float* __restrict__ W3, const float* __restrict__ al3,
                            const float* __restrict__ ar3,
                            float* __restrict__ aleff2, float* __restrict__ areff2,
                            float* __restrict__ aleff3, float* __restrict__ areff3,
                            float* __restrict__ W4t2,
                            unsigned* __restrict__ wfhi, unsigned* __restrict__ wflo,
                            int* __restrict__ counts, int* __restrict__ cursor) {
    int i = blockIdx.x * blockDim.x + threadIdx.x;
    if (i < 1536) {
        if (i < N_NODES + 1) counts[i] = 0;
        return;
    }
    i -= 1536;
    if (i < 1536) {
        if (i < N_NODES) cursor[i] = 0;
        return;
    }
    i -= 1536;
    if (i < 1024) {  // aleff2 / areff2
        int lr = i >> 9; i &= 511;
        int h = i >> 6, k = i & 63;
        const float* a = lr ? ar2 : al2;
        float s = 0.f;
        for (int f = 0; f < 64; ++f)
            s = fmaf(W2[(size_t)k * 512 + h * 64 + f], a[h * 64 + f], s);
        (lr ? areff2 : aleff2)[h * 64 + k] = s;
        return;
    }
    i -= 1024;
    if (i < 1024) {  // aleff3 / areff3
        int lr = i >> 9; i &= 511;
        int h = i >> 6, k = i & 63;
        const float* a = lr ? ar3 : al3;
        float s = 0.f;
        for (int f = 0; f < 32; ++f)
            s = fmaf(W3[(size_t)k * 256 + h * 32 + f], a[h * 32 + f], s);
        (lr ? areff3 : aleff3)[h * 64 + k] = s;
        return;
    }
    i -= 1024;
    if (i < 16 * 512 * 4) {  // W4t2
        int kg = i >> 11, rem = i & 2047;
        int c = rem >> 2, j = rem & 3;
        W4t2[i] = W2[(size_t)(kg * 4 + j) * 512 + c];
        return;
    }
    i -= 16 * 512 * 4;
    if (i < 16384) {  // wfhi / wflo
        int plane = i >> 13;
        int rem = i & 8191;
        int j2 = rem & 3, l = (rem >> 2) & 63;
        int ks = (rem >> 8) & 1, nt = (rem >> 9) & 1, h = (rem >> 10) & 7;
        int col = h * 32 + nt * 16 + (l & 15);
        int kb = ks * 32 + (l >> 4) * 8 + 2 * j2;
        unsigned parts[2];
        #pragma unroll
        for (int q = 0; q < 2; ++q) {
            float w = W3[(size_t)(kb + q) * 256 + col];
            unsigned short hi = f2bf(w);
            parts[q] = plane ? (unsigned)f2bf(w - bf2f(hi)) : (unsigned)hi;
        }
        unsigned word = parts[0] | (parts[1] << 16);
        (plane ? wflo : wfhi)[rem] = word;
    }
}

__global__ void hist_kernel(const int* __restrict__ dst, int* __restrict__ counts) {
    int e = blockIdx.x * blockDim.x + threadIdx.x;
    if (e < N_EDGES) atomicAdd(&counts[dst[e]], 1);
}

__global__ void scan_kernel(const int* __restrict__ counts, int* __restrict__ row_ptr) {
    __shared__ int part[256];
    int t = threadIdx.x;
    const int CH = (N_NODES + 255) / 256;
    int base = t * CH;
    int loc[8];
    int s = 0;
    for (int i = 0; i < CH; ++i) {
        int idx = base + i;
        int v = (idx < N_NODES) ? counts[idx] : 0;
        loc[i] = s;
        s += v;
    }
    part[t] = s;
    __syncthreads();
    if (t == 0) {
        int a = 0;
        for (int i = 0; i < 256; ++i) { int v = part[i]; part[i] = a; a += v; }
        row_ptr[N_NODES] = a;
    }
    __syncthreads();
    int p0 = part[t];
    for (int i = 0; i < CH; ++i) {
        int idx = base + i;
        if (idx < N_NODES) row_ptr[idx] = p0 + loc[i];
    }
}

__global__ void scatter_kernel(const int* __restrict__ dst, const int* __restrict__ row_ptr,
                               int* __restrict__ cursor, int* __restrict__ tmp_eid) {
    int e = blockIdx.x * blockDim.x + threadIdx.x;
    if (e < N_EDGES) {
        int d = dst[e];
        int pos = row_ptr[d] + atomicAdd(&cursor[d], 1);
        tmp_eid[pos] = e;
    }
}

// per-node sort by edge id -> deterministic stable order
__global__ void sort_csr_kernel(const int* __restrict__ row_ptr, const int* __restrict__ tmp_eid,
                                const int* __restrict__ src, int* __restrict__ csr_src) {
    int wid = (blockIdx.x * blockDim.x + threadIdx.x) >> 6;
    int lane = threadIdx.x & 63;
    if (wid >= N_NODES) return;
    int r0 = row_ptr[wid], deg = row_ptr[wid + 1] - r0;
    for (int base = 0; base < deg; base += 64) {
        int i = base + lane;
        int my = (i < deg) ? tmp_eid[r0 + i] : 0x7fffffff;
        int rank = 0;
        for (int b2 = 0; b2 < deg; b2 += 64) {
            int other = (b2 + lane < deg) ? tmp_eid[r0 + b2 + lane] : 0x7fffffff;
            int cnt2 = min(deg - b2, 64);
            for (int j = 0; j < cnt2; ++j) {
                int oj = __shfl(other, j);
                rank += (oj < my) ? 1 : 0;
            }
        }
        if (i < deg) csr_src[r0 + rank] = src[my];
    }
}

// ---------------- f32 tiled GEMM (layer 1): 32x32 tiles (752 blocks) ----------

#define GM 32
#define GN 32
#define GK 32

__global__ __launch_bounds__(256) void gemm_f32(const float* __restrict__ A,
                                                const float* __restrict__ B,
                                                float* __restrict__ C,
                                                int M, int N, int K) {
    __shared__ float As[GK][GM + 2];
    __shared__ float Bs[GK][GN + 2];
    int t = threadIdx.x;
    int col0 = blockIdx.x * GN, row0 = blockIdx.y * GM;
    int tx = t & 15, ty = t >> 4;
    int am = t >> 3, ak = (t & 7) * 4;
    int bk = t >> 3, bn = (t & 7) * 4;
    float acc[2][2] = {};
    for (int k0 = 0; k0 < K; k0 += GK) {
        int gr = row0 + am;
        float4 av = (gr < M) ? *(const float4*)&A[(size_t)gr * K + k0 + ak]
                             : make_float4(0.f, 0.f, 0.f, 0.f);
        float4 bv = *(const float4*)&B[(size_t)(k0 + bk) * N + col0 + bn];
        __syncthreads();
        As[ak + 0][am] = av.x; As[ak + 1][am] = av.y;
        As[ak + 2][am] = av.z; As[ak + 3][am] = av.w;
        *(float4*)&Bs[bk][bn] = bv;
        __syncthreads();
        #pragma unroll
        for (int kk = 0; kk < GK; ++kk) {
            float2 a2 = *(const float2*)&As[kk][ty * 2];
            float2 b2 = *(const float2*)&Bs[kk][tx * 2];
            acc[0][0] = fmaf(a2.x, b2.x, acc[0][0]);
            acc[0][1] = fmaf(a2.x, b2.y, acc[0][1]);
            acc[1][0] = fmaf(a2.y, b2.x, acc[1][0]);
            acc[1][1] = fmaf(a2.y, b2.y, acc[1][1]);
        }
    }
    #pragma unroll
    for (int i = 0; i < 2; ++i) {
        int gr = row0 + ty * 2 + i;
        if (gr < M) {
            float2 v = make_float2(acc[i][0], acc[i][1]);
            *(float2*)&C[(size_t)gr * N + col0 + tx * 2] = v;
        }
    }
}

// ---------------- el/er kernels ----------------

__global__ void elr_feat_kernel(const float* __restrict__ feat, const float* __restrict__ al,
                                const float* __restrict__ ar, float* __restrict__ el,
                                float* __restrict__ er, int RH) {
    int idx = blockIdx.x * blockDim.x + threadIdx.x;
    if (idx >= RH) return;
    int h = idx & (HEADS - 1);
    const float* fp = feat + (size_t)idx * HIDDEN;
    float sl = 0.f, sr = 0.f;
    for (int f = 0; f < HIDDEN; ++f) {
        float v = fp[f];
        sl = fmaf(v, al[h * HIDDEN + f], sl);
        sr = fmaf(v, ar[h * HIDDEN + f], sr);
    }
    el[idx] = sl;
    er[idx] = sr;
}

__global__ void elr_row_kernel(const float* __restrict__ X, const float* __restrict__ alv,
                               const float* __restrict__ arv, float* __restrict__ el,
                               float* __restrict__ er, int R) {
    int r = blockIdx.x * blockDim.x + threadIdx.x;
    if (r >= R) return;
    const float4* x4 = (const float4*)(X + (size_t)r * 64);
    float sl[8] = {}, sr[8] = {};
    for (int kg = 0; kg < 16; ++kg) {
        float4 xv = x4[kg];
        #pragma unroll
        for (int h = 0; h < 8; ++h) {
            float4 a = *(const float4*)&alv[h * 64 + kg * 4];
            float4 b = *(const float4*)&arv[h * 64 + kg * 4];
            sl[h] = fmaf(xv.x, a.x, fmaf(xv.y, a.y, fmaf(xv.z, a.z, fmaf(xv.w, a.w, sl[h]))));
            sr[h] = fmaf(xv.x, b.x, fmaf(xv.y, b.y, fmaf(xv.z, b.z, fmaf(xv.w, b.w, sr[h]))));
        }
    }
    float* elp = el + (size_t)r * 8;
    float* erp = er + (size_t)r * 8;
    #pragma unroll
    for (int h = 0; h < 8; ++h) { elp[h] = sl[h]; erp[h] = sr[h]; }
}

__device__ __forceinline__ float gelu_exact(float v) {
    return 0.5f * v * (1.0f + erff(v * 0.70710678118654752440f));
}

// ---------------- layer-1 aggregation: wave per (node, head-pair), src in registers ----------
__global__ __launch_bounds__(256) void agg_l1(
    const float* __restrict__ feat, const float* __restrict__ el, const float* __restrict__ er,
    const float* __restrict__ bias, const int* __restrict__ row_ptr,
    const int* __restrict__ csr_src, float* __restrict__ out) {
    int n = blockIdx.x;
    int t = threadIdx.x, wv = t >> 6, lane = t & 63;
    int h0 = 2 * wv;
    int r0 = row_ptr[n], deg = row_ptr[n + 1] - r0;
    float2 erv = *(const float2*)&er[n * 8 + h0];
    float den0 = 0.f, den1 = 0.f, a0 = 0.f, a1 = 0.f;
    for (int c0 = 0; c0 < deg; c0 += 64) {
        int cnt = min(deg - c0, 64);
        int src_r = (lane < cnt) ? csr_src[r0 + c0 + lane] : 0;
        auto do_edge = [&](int s) {
            float2 elv = *(const float2*)&el[s * 8 + h0];
            float x0 = feat[((size_t)s * 8 + h0) * 64 + lane];
            float x1 = feat[((size_t)s * 8 + h0 + 1) * 64 + lane];
            float e0 = elv.x + erv.x; e0 = e0 > 0.f ? e0 : 0.2f * e0;
            float e1 = elv.y + erv.y; e1 = e1 > 0.f ? e1 : 0.2f * e1;
            float w0 = __expf(e0), w1 = __expf(e1);
            den0 += w0; den1 += w1;
            a0 = fmaf(w0, x0, a0);
            a1 = fmaf(w1, x1, a1);
        };
        int i = 0;
        for (; i + 2 <= cnt; i += 2) {
            int s0 = __builtin_amdgcn_readlane(src_r, i);
            int s1 = __builtin_amdgcn_readlane(src_r, i + 1);
            do_edge(s0);
            do_edge(s1);
        }
        if (i < cnt) do_edge(__builtin_amdgcn_readlane(src_r, i));
    }
    float i0 = deg ? 1.f / den0 : 0.f;
    float i1 = deg ? 1.f / den1 : 0.f;
    float v0 = a0 * i0 + bias[h0 * 64 + lane];
    float v1 = a1 * i1 + bias[(h0 + 1) * 64 + lane];
    out[((size_t)n * 8 + h0) * 64 + lane] = gelu_exact(v0);
    out[((size_t)n * 8 + h0 + 1) * 64 + lane] = gelu_exact(v1);
}

// ---------------- layer 2: LDS-staged weights + register-blocked transform ----------------
template <int FOUT, bool GELU, int P>
__global__ __launch_bounds__(256, 4) void agg_fused4(
    const float* __restrict__ X,
    const float* __restrict__ el, const float* __restrict__ er,
    const float* __restrict__ W4t,
    const float* __restrict__ bias,
    const int* __restrict__ row_ptr, const int* __restrict__ csr_src,
    float* __restrict__ out)
{
    constexpr int TOT = 8 * FOUT;
    constexpr int KSPLIT = 2;
    constexpr int KGPT = 8;
    constexpr int FELEM = (FOUT == 32) ? 2 : 4;
    constexpr int FQn = FOUT / FELEM;
    constexpr int TPK = 8 * FQn;
    constexpr int FQ4 = FOUT / 4;
    constexpr int PTS = FOUT + 4;
    constexpr int WPFL = (KSPLIT * 64 * PTS > 64 * 64) ? KSPLIT * 64 * PTS : 64 * 64;
    constexpr int GRPS = P / 8;
    constexpr int CHUNK = 64;

    int nb = blockIdx.x;
    int n = nb / GRPS, pg = nb - n * GRPS;
    int p0 = pg * 8;
    int r0 = row_ptr[n], deg = row_ptr[n + 1] - r0;
    int t = threadIdx.x, wv = t >> 6, lane = t & 63;

    __shared__ float inv_s[64];
    __shared__ float acc_s[8][8][68];
    __shared__ float wp_lds[WPFL];

    float agg0[8], agg1[8];
    #pragma unroll
    for (int h = 0; h < 8; ++h) { agg0[h] = 0.f; agg1[h] = 0.f; }
    float den = 0.f;

    int elbase_n = (n * P + p0) * 8;
    int pA = p0 + wv * 2;
    float erv_t = er[elbase_n + lane];

    for (int c0 = 0; c0 < deg; c0 += CHUNK) {
        int cnt = min(deg - c0, CHUNK);
        int src_r = (lane < cnt) ? csr_src[r0 + c0 + lane] : 0;
        __syncthreads();
        for (int j = t; j < cnt * 64; j += 256) {
            int i = j >> 6;
            int s = __builtin_amdgcn_readlane(src_r, i);
            float e = el[(s * P + p0) * 8 + lane] + erv_t;
            e = e > 0.f ? e : 0.2f * e;
            wp_lds[i * 64 + lane] = __expf(e);
        }
        __syncthreads();
        if (t < 64) {
            for (int i = 0; i < cnt; ++i) den += wp_lds[i * 64 + t];
        }
        auto edge_fma = [&](int i) {
            int s = __builtin_amdgcn_readlane(src_r, i);
            const float* wp = &wp_lds[i * 64 + wv * 16];
            float4 w0 = *(const float4*)wp;
            float4 w1 = *(const float4*)(wp + 4);
            float4 w2 = *(const float4*)(wp + 8);
            float4 w3 = *(const float4*)(wp + 12);
            int xb = (s * P + pA) * 64 + lane;
            float xv0 = X[xb];
            float xv1 = X[xb + 64];
            agg0[0] = fmaf(w0.x, xv0, agg0[0]);
            agg0[1] = fmaf(w0.y, xv0, agg0[1]);
            agg0[2] = fmaf(w0.z, xv0, agg0[2]);
            agg0[3] = fmaf(w0.w, xv0, agg0[3]);
            agg0[4] = fmaf(w1.x, xv0, agg0[4]);
            agg0[5] = fmaf(w1.y, xv0, agg0[5]);
            agg0[6] = fmaf(w1.z, xv0, agg0[6]);
            agg0[7] = fmaf(w1.w, xv0, agg0[7]);
            agg1[0] = fmaf(w2.x, xv1, agg1[0]);
            agg1[1] = fmaf(w2.y, xv1, agg1[1]);
            agg1[2] = fmaf(w2.z, xv1, agg1[2]);
            agg1[3] = fmaf(w2.w, xv1, agg1[3]);
            agg1[4] = fmaf(w3.x, xv1, agg1[4]);
            agg1[5] = fmaf(w3.y, xv1, agg1[5]);
            agg1[6] = fmaf(w3.z, xv1, agg1[6]);
            agg1[7] = fmaf(w3.w, xv1, agg1[7]);
        };
        int i = 0;
        for (; i + 2 <= cnt; i += 2) { edge_fma(i); edge_fma(i + 1); }
        if (i < cnt) edge_fma(i);
    }
    if (t < 64) inv_s[t] = deg ? 1.f / den : 0.f;
    __syncthreads();
    {
        int pl0 = wv * 2;
        #pragma unroll
        for (int h = 0; h < 8; ++h) {
            acc_s[pl0][h][lane] = agg0[h] * inv_s[pl0 * 8 + h];
            acc_s[pl0 + 1][h][lane] = agg1[h] * inv_s[pl0 * 8 + 8 + h];
        }
    }
    __syncthreads();

    {
        int kq = t / TPK;
        int rem = t - kq * TPK;
        int h = rem / FQn;
        int ft = rem - h * FQn;
        int f0 = ft * FELEM;
        float part[8][FELEM];
        #pragma unroll
        for (int pl = 0; pl < 8; ++pl)
            #pragma unroll
            for (int j = 0; j < FELEM; ++j) part[pl][j] = 0.f;
        #pragma unroll
        for (int kk = 0; kk < KGPT; ++kk) {
            int kg = kq * KGPT + kk;
            float4 wr[FELEM];
            #pragma unroll
            for (int j = 0; j < FELEM; ++j)
                wr[j] = *(const float4*)&W4t[(size_t)(kg * TOT + h * FOUT + f0 + j) * 4];
            #pragma unroll
            for (int pl = 0; pl < 8; ++pl) {
                float4 a4 = *(const float4*)&acc_s[pl][h][kg * 4];
                #pragma unroll
                for (int j = 0; j < FELEM; ++j)
                    part[pl][j] = fmaf(a4.x, wr[j].x, fmaf(a4.y, wr[j].y,
                                  fmaf(a4.z, wr[j].z, fmaf(a4.w, wr[j].w, part[pl][j]))));
            }
        }
        #pragma unroll
        for (int pl = 0; pl < 8; ++pl) {
            float* dstp = &wp_lds[((kq * 8 + pl) * 8 + h) * PTS + f0];
            if (FELEM == 4)
                *(float4*)dstp = make_float4(part[pl][0], part[pl][1], part[pl][2], part[pl][3]);
            else
                *(float2*)dstp = make_float2(part[pl][0], part[pl][1]);
        }
    }
    __syncthreads();

    {
        constexpr int NQ = 2 * TOT;
        for (int q = t; q < NQ; q += 256) {
            int pl = q / (TOT / 4);
            int rem = q - pl * (TOT / 4);
            int h = rem / FQ4, fq = rem - h * FQ4;
            int f0 = fq * 4;
            float4 acc4 = *(const float4*)&wp_lds[((0 * 8 + pl) * 8 + h) * PTS + f0];
            #pragma unroll
            for (int kq = 1; kq < KSPLIT; ++kq) {
                float4 pv = *(const float4*)&wp_lds[((kq * 8 + pl) * 8 + h) * PTS + f0];
                acc4.x += pv.x; acc4.y += pv.y; acc4.z += pv.z; acc4.w += pv.w;
            }
            float4 b4 = *(const float4*)&bias[h * FOUT + f0];
            acc4.x += b4.x; acc4.y += b4.y; acc4.z += b4.z; acc4.w += b4.w;
            if (GELU) {
                acc4.x = gelu_exact(acc4.x); acc4.y = gelu_exact(acc4.y);
                acc4.z = gelu_exact(acc4.z); acc4.w = gelu_exact(acc4.w);
            }
            *(float4*)&out[(size_t)(n * P + p0 + pl) * TOT + h * FOUT + f0] = acc4;
        }
    }
}

// ---------------- layer 3: register-src aggregation + split-h MFMA transform ----------------
// Block = (node, 16-p group), 6000 blocks. LDS halved to accH[4][16][68] (17.4 KB)
// by doing pack+MFMA in 2 rounds over heads -> 6 blocks/CU (24 waves, 75%).
__global__ __launch_bounds__(256, 6) void agg_mfma6(
    const float* __restrict__ X,        // h2 [N*64, 64]
    const float* __restrict__ el, const float* __restrict__ er,  // [N*64, 8]
    const unsigned* __restrict__ wfhi, const unsigned* __restrict__ wflo,
    const float* __restrict__ bias,     // [256]
    const int* __restrict__ row_ptr, const int* __restrict__ csr_src,
    float* __restrict__ out)            // [N*64, 256]
{
    int b = blockIdx.x;                  // 6000 = 1500 n * 4 pg
    int n = b >> 2, pg = b & 3;
    int p0 = pg * 16;
    int r0 = row_ptr[n], deg = row_ptr[n + 1] - r0;
    int t = threadIdx.x, wv = t >> 6, lane = t & 63;
    int pA = p0 + wv * 4;

    __shared__ unsigned accH[4][16][68];   // [h in round][pl][k] packed bf16 hi|lo

    int c = lane & 31;                     // (q,h) = (c>>3, c&7)
    float erv = er[(n * 64 + pA) * 8 + c];

    float agg[4][8];
    #pragma unroll
    for (int q = 0; q < 4; ++q)
        #pragma unroll
        for (int h = 0; h < 8; ++h) agg[q][h] = 0.f;
    float den_half = 0.f;

    for (int c0 = 0; c0 < deg; c0 += 64) {
        int cnt = min(deg - c0, 64);
        int src_r = (lane < cnt) ? csr_src[r0 + c0 + lane] : 0;
        for (int it = 0; it < cnt; it += 4) {
            int i1 = min(it + 1, cnt - 1), i2 = min(it + 2, cnt - 1), i3 = min(it + 3, cnt - 1);
            int s0 = __builtin_amdgcn_readlane(src_r, it);
            int s1 = __builtin_amdgcn_readlane(src_r, i1);
            int s2 = __builtin_amdgcn_readlane(src_r, i2);
            int s3 = __builtin_amdgcn_readlane(src_r, i3);
            bool v1 = it + 1 < cnt, v2 = it + 2 < cnt, v3 = it + 3 < cnt;
            int sA = (lane < 32) ? s0 : s1;
            int sB = (lane < 32) ? s2 : s3;
            float eA = el[(sA * 64 + pA) * 8 + c] + erv;
            float eB = el[(sB * 64 + pA) * 8 + c] + erv;
            eA = eA > 0.f ? eA : 0.2f * eA;
            eB = eB > 0.f ? eB : 0.2f * eB;
            if (lane >= 32 && !v1) eA = -1e30f;
            if (lane < 32 && !v2) eB = -1e30f;
            if (lane >= 32 && !v3) eB = -1e30f;
            float wA = __expf(eA), wB = __expf(eB);
            den_half += wA + wB;
            int xb0 = (s0 * 64 + pA) * 64 + lane;
            int xb1 = (s1 * 64 + pA) * 64 + lane;
            int xb2 = (s2 * 64 + pA) * 64 + lane;
            int xb3 = (s3 * 64 + pA) * 64 + lane;
            float x0[4], x1[4], x2[4], x3[4];
            #pragma unroll
            for (int q = 0; q < 4; ++q) x0[q] = X[xb0 + q * 64];
            #pragma unroll
            for (int q = 0; q < 4; ++q) x1[q] = X[xb1 + q * 64];
            #pragma unroll
            for (int q = 0; q < 4; ++q) x2[q] = X[xb2 + q * 64];
            #pragma unroll
            for (int q = 0; q < 4; ++q) x3[q] = X[xb3 + q * 64];
            #pragma unroll
            for (int q = 0; q < 4; ++q) {
                #pragma unroll
                for (int h = 0; h < 8; ++h) {
                    agg[q][h] = fmaf(rdlanef(wA, q * 8 + h), x0[q], agg[q][h]);
                    agg[q][h] = fmaf(rdlanef(wA, 32 + q * 8 + h), x1[q], agg[q][h]);
                    agg[q][h] = fmaf(rdlanef(wB, q * 8 + h), x2[q], agg[q][h]);
                    agg[q][h] = fmaf(rdlanef(wB, 32 + q * 8 + h), x3[q], agg[q][h]);
                }
            }
        }
    }
    float den = den_half + __shfl(den_half, lane ^ 32);
    float inv = deg ? 1.f / den : 0.f;

    int m16 = lane & 15, g = lane >> 4;
    #pragma unroll
    for (int r = 0; r < 2; ++r) {
        if (r) __syncthreads();   // prev round's MFMA reads done before overwrite
        // pack heads [4r, 4r+4): wave wv packs its 4 p's
        #pragma unroll
        for (int q = 0; q < 4; ++q) {
            int pl = wv * 4 + q;
            #pragma unroll
            for (int hh = 0; hh < 4; ++hh) {
                int h = 4 * r + hh;
                float iv = rdlanef(inv, q * 8 + h);
                accH[hh][pl][lane] = packbf(agg[q][h] * iv);
            }
        }
        __syncthreads();
        // MFMA: wave wv handles head h = 4r + wv
        int h = 4 * r + wv;
        bf16x8 a_hi[2], a_lo[2];
        #pragma unroll
        for (int ks = 0; ks < 2; ++ks) {
            const unsigned* ap = &accH[wv][m16][ks * 32 + g * 8];
            uint4 q0 = *(const uint4*)ap;
            uint4 q1 = *(const uint4*)(ap + 4);
            a_hi[ks][0] = (short)(q0.x & 0xffffu); a_lo[ks][0] = (short)(q0.x >> 16);
            a_hi[ks][1] = (short)(q0.y & 0xffffu); a_lo[ks][1] = (short)(q0.y >> 16);
            a_hi[ks][2] = (short)(q0.z & 0xffffu); a_lo[ks][2] = (short)(q0.z >> 16);
            a_hi[ks][3] = (short)(q0.w & 0xffffu); a_lo[ks][3] = (short)(q0.w >> 16);
            a_hi[ks][4] = (short)(q1.x & 0xffffu); a_lo[ks][4] = (short)(q1.x >> 16);
            a_hi[ks][5] = (short)(q1.y & 0xffffu); a_lo[ks][5] = (short)(q1.y >> 16);
            a_hi[ks][6] = (short)(q1.z & 0xffffu); a_lo[ks][6] = (short)(q1.z >> 16);
            a_hi[ks][7] = (short)(q1.w & 0xffffu); a_lo[ks][7] = (short)(q1.w >> 16);
        }
        #pragma unroll
        for (int nt = 0; nt < 2; ++nt) {
            f32x4 D = {0.f, 0.f, 0.f, 0.f};
            #pragma unroll
            for (int ks = 0; ks < 2; ++ks) {
                size_t fb = (size_t)(((h * 2 + nt) * 2 + ks) * 64 + lane) * 4;
                bf16x8 b_hi = *(const bf16x8*)&wfhi[fb];
                bf16x8 b_lo = *(const bf16x8*)&wflo[fb];
                D = __builtin_amdgcn_mfma_f32_16x16x32_bf16(a_hi[ks], b_hi, D, 0, 0, 0);
                D = __builtin_amdgcn_mfma_f32_16x16x32_bf16(a_hi[ks], b_lo, D, 0, 0, 0);
                D = __builtin_amdgcn_mfma_f32_16x16x32_bf16(a_lo[ks], b_hi, D, 0, 0, 0);
            }
            float bv = bias[h * 32 + nt * 16 + m16];
            size_t ob = ((size_t)(n * 64) + p0 + g * 4) * 256 + h * 32 + nt * 16 + m16;
            out[ob]       = D[0] + bv;
            out[ob + 256] = D[1] + bv;
            out[ob + 512] = D[2] + bv;
            out[ob + 768] = D[3] + bv;
        }
    }
}

// ---------------- launch ----------------

extern "C" void kernel_launch(void* const* d_in, const int* in_sizes, int n_in,
                              void* d_out, int out_size, void* d_ws, size_t ws_size,
                              hipStream_t stream) {
    const float* node = (const float*)d_in[0];
    const int* src = (const int*)d_in[1];
    const int* dst = (const int*)d_in[2];
    const float* W1 = (const float*)d_in[3];
    const float* al1 = (const float*)d_in[4];
    const float* ar1 = (const float*)d_in[5];
    const float* b1 = (const float*)d_in[6];
    const float* W2 = (const float*)d_in[7];
    const float* al2 = (const float*)d_in[8];
    const float* ar2 = (const float*)d_in[9];
    const float* b2 = (const float*)d_in[10];
    const float* W3 = (const float*)d_in[11];
    const float* al3 = (const float*)d_in[12];
    const float* ar3 = (const float*)d_in[13];
    const float* b3 = (const float*)d_in[14];
    float* out = (float*)d_out;

    char* ws = (char*)d_ws;
    size_t off = 0;
    auto alloc = [&](size_t nb) -> char* {
        char* q = ws + off;
        off += (nb + 255) & ~(size_t)255;
        return q;
    };
    int* counts   = (int*)alloc((N_NODES + 1) * sizeof(int));
    int* cursor   = (int*)alloc(N_NODES * sizeof(int));
    int* row_ptr  = (int*)alloc((N_NODES + 1) * sizeof(int));
    int* tmp_eid  = (int*)alloc(N_EDGES * sizeof(int));
    int* csr_src  = (int*)alloc(N_EDGES * sizeof(int));
    float* feat1  = (float*)alloc((size_t)N_NODES * 8 * 64 * 4);
    float* el1    = (float*)alloc((size_t)N_NODES * 8 * 4);
    float* er1    = (float*)alloc((size_t)N_NODES * 8 * 4);
    float* h1     = (float*)alloc((size_t)N_NODES * 8 * 64 * 4);
    float* aleff2 = (float*)alloc(8 * 64 * 4);
    float* areff2 = (float*)alloc(8 * 64 * 4);
    float* el2    = (float*)alloc((size_t)N_NODES * 8 * 8 * 4);
    float* er2    = (float*)alloc((size_t)N_NODES * 8 * 8 * 4);
    float* h2     = (float*)alloc((size_t)N_NODES * 64 * 64 * 4);
    float* aleff3 = (float*)alloc(8 * 64 * 4);
    float* areff3 = (float*)alloc(8 * 64 * 4);
    float* el3    = (float*)alloc((size_t)N_NODES * 64 * 8 * 4);
    float* er3    = (float*)alloc((size_t)N_NODES * 64 * 8 * 4);
    float* W4t2   = (float*)alloc((size_t)16 * 512 * 4 * 4);
    unsigned* wfhi = (unsigned*)alloc((size_t)8192 * 4);
    unsigned* wflo = (unsigned*)alloc((size_t)8192 * 4);

    const int PREP_T = 1536 + 1536 + 1024 + 1024 + 16 * 512 * 4 + 16384;
    prep_kernel<<<(PREP_T + 255) / 256, 256, 0, stream>>>(
        W2, al2, ar2, W3, al3, ar3, aleff2, areff2, aleff3, areff3, W4t2, wfhi, wflo,
        counts, cursor);

    hist_kernel<<<(N_EDGES + 255) / 256, 256, 0, stream>>>(dst, counts);
    scan_kernel<<<1, 256, 0, stream>>>(counts, row_ptr);
    scatter_kernel<<<(N_EDGES + 255) / 256, 256, 0, stream>>>(dst, row_ptr, cursor, tmp_eid);
    sort_csr_kernel<<<(N_NODES * 64 + 255) / 256, 256, 0, stream>>>(row_ptr, tmp_eid, src, csr_src);

    // ---- layer 1 ----
    dim3 g1((512 + GN - 1) / GN, (N_NODES + GM - 1) / GM);
    gemm_f32<<<g1, 256, 0, stream>>>(node, W1, feat1, N_NODES, 512, IN_FEAT);
    elr_feat_kernel<<<(N_NODES * 8 + 255) / 256, 256, 0, stream>>>(feat1, al1, ar1, el1, er1, N_NODES * 8);
    agg_l1<<<N_NODES, 256, 0, stream>>>(feat1, el1, er1, b1, row_ptr, csr_src, h1);

    // ---- layer 2 ----
    elr_row_kernel<<<(N_NODES * 8 + 255) / 256, 256, 0, stream>>>(h1, aleff2, areff2, el2, er2, N_NODES * 8);
    agg_fused4<64, true, 8><<<N_NODES, 256, 0, stream>>>(h1, el2, er2, W4t2, b2, row_ptr, csr_src, h2);

    // ---- layer 3 ----
    elr_row_kernel<<<(N_NODES * 64 + 255) / 256, 256, 0, stream>>>(h2, aleff3, areff3, el3, er3, N_NODES * 64);
    agg_mfma6<<<N_NODES * 4, 256, 0, stream>>>(h2, el3, er3, wfhi, wflo, b3, row_ptr, csr_src, out);
}

// Round 11
// 165.376 us; speedup vs baseline: 1.5093x; 1.0203x over previous
//
#include <hip/hip_runtime.h>
#include <math.h>

#define N_NODES 1500
#define N_EDGES 12000
#define IN_FEAT 512
#define HIDDEN 64
#define OUT_FEAT 32
#define HEADS 8

typedef short bf16x8 __attribute__((ext_vector_type(8)));
typedef float f32x4 __attribute__((ext_vector_type(4)));

__device__ __forceinline__ unsigned short f2bf(float f) {
    unsigned u = __float_as_uint(f);
    u += 0x7fff + ((u >> 16) & 1);   // RNE
    return (unsigned short)(u >> 16);
}
__device__ __forceinline__ float bf2f(unsigned short b) {
    return __uint_as_float(((unsigned)b) << 16);
}
__device__ __forceinline__ unsigned packbf(float a) {
    unsigned short hi = f2bf(a);
    unsigned short lo = f2bf(a - bf2f(hi));
    return (unsigned)hi | ((unsigned)lo << 16);
}
__device__ __forceinline__ float rdlanef(float v, int c) {
    return __uint_as_float(__builtin_amdgcn_readlane(__float_as_uint(v), c));
}

// ---------------- fused prep: zeros + att-eff vectors + W2 reshuffle + W3 hi/lo frags ----
// W4t2[(kg*512 + c)*4 + j] = W2[(kg*4+j)*512 + c]
// wfhi/wflo: [(h*2+nt)*2+ks][lane][4 words]; word j2 = bf16(k=base+2j2) | bf16(k=base+2j2+1)<<16

__global__ void prep_kernel(const float* __restrict__ W2, const float* __restrict__ al2,
                            const float* __restrict__ ar2,
                            const float* __restrict__ W3, const float* __restrict__ al3,
                            const float* __restrict__ ar3,
                            float* __restrict__ aleff2, float* __restrict__ areff2,
                            float* __restrict__ aleff3, float* __restrict__ areff3,
                            float* __restrict__ W4t2,
                            unsigned* __restrict__ wfhi, unsigned* __restrict__ wflo,
                            int* __restrict__ counts, int* __restrict__ cursor) {
    int i = blockIdx.x * blockDim.x + threadIdx.x;
    if (i < 1536) {
        if (i < N_NODES + 1) counts[i] = 0;
        return;
    }
    i -= 1536;
    if (i < 1536) {
        if (i < N_NODES) cursor[i] = 0;
        return;
    }
    i -= 1536;
    if (i < 1024) {  // aleff2 / areff2
        int lr = i >> 9; i &= 511;
        int h = i >> 6, k = i & 63;
        const float* a = lr ? ar2 : al2;
        float s = 0.f;
        for (int f = 0; f < 64; ++f)
            s = fmaf(W2[(size_t)k * 512 + h * 64 + f], a[h * 64 + f], s);
        (lr ? areff2 : aleff2)[h * 64 + k] = s;
        return;
    }
    i -= 1024;
    if (i < 1024) {  // aleff3 / areff3
        int lr = i >> 9; i &= 511;
        int h = i >> 6, k = i & 63;
        const float* a = lr ? ar3 : al3;
        float s = 0.f;
        for (int f = 0; f < 32; ++f)
            s = fmaf(W3[(size_t)k * 256 + h * 32 + f], a[h * 32 + f], s);
        (lr ? areff3 : aleff3)[h * 64 + k] = s;
        return;
    }
    i -= 1024;
    if (i < 16 * 512 * 4) {  // W4t2
        int kg = i >> 11, rem = i & 2047;
        int c = rem >> 2, j = rem & 3;
        W4t2[i] = W2[(size_t)(kg * 4 + j) * 512 + c];
        return;
    }
    i -= 16 * 512 * 4;
    if (i < 16384) {  // wfhi / wflo
        int plane = i >> 13;
        int rem = i & 8191;
        int j2 = rem & 3, l = (rem >> 2) & 63;
        int ks = (rem >> 8) & 1, nt = (rem >> 9) & 1, h = (rem >> 10) & 7;
        int col = h * 32 + nt * 16 + (l & 15);
        int kb = ks * 32 + (l >> 4) * 8 + 2 * j2;
        unsigned parts[2];
        #pragma unroll
        for (int q = 0; q < 2; ++q) {
            float w = W3[(size_t)(kb + q) * 256 + col];
            unsigned short hi = f2bf(w);
            parts[q] = plane ? (unsigned)f2bf(w - bf2f(hi)) : (unsigned)hi;
        }
        unsigned word = parts[0] | (parts[1] << 16);
        (plane ? wflo : wfhi)[rem] = word;
    }
}

__global__ void hist_kernel(const int* __restrict__ dst, int* __restrict__ counts) {
    int e = blockIdx.x * blockDim.x + threadIdx.x;
    if (e < N_EDGES) atomicAdd(&counts[dst[e]], 1);
}

__global__ void scan_kernel(const int* __restrict__ counts, int* __restrict__ row_ptr) {
    __shared__ int part[256];
    int t = threadIdx.x;
    const int CH = (N_NODES + 255) / 256;
    int base = t * CH;
    int loc[8];
    int s = 0;
    for (int i = 0; i < CH; ++i) {
        int idx = base + i;
        int v = (idx < N_NODES) ? counts[idx] : 0;
        loc[i] = s;
        s += v;
    }
    part[t] = s;
    __syncthreads();
    if (t == 0) {
        int a = 0;
        for (int i = 0; i < 256; ++i) { int v = part[i]; part[i] = a; a += v; }
        row_ptr[N_NODES] = a;
    }
    __syncthreads();
    int p0 = part[t];
    for (int i = 0; i < CH; ++i) {
        int idx = base + i;
        if (idx < N_NODES) row_ptr[idx] = p0 + loc[i];
    }
}

__global__ void scatter_kernel(const int* __restrict__ dst, const int* __restrict__ row_ptr,
                               int* __restrict__ cursor, int* __restrict__ tmp_eid) {
    int e = blockIdx.x * blockDim.x + threadIdx.x;
    if (e < N_EDGES) {
        int d = dst[e];
        int pos = row_ptr[d] + atomicAdd(&cursor[d], 1);
        tmp_eid[pos] = e;
    }
}

// per-node sort by edge id -> deterministic stable order
__global__ void sort_csr_kernel(const int* __restrict__ row_ptr, const int* __restrict__ tmp_eid,
                                const int* __restrict__ src, int* __restrict__ csr_src) {
    int wid = (blockIdx.x * blockDim.x + threadIdx.x) >> 6;
    int lane = threadIdx.x & 63;
    if (wid >= N_NODES) return;
    int r0 = row_ptr[wid], deg = row_ptr[wid + 1] - r0;
    for (int base = 0; base < deg; base += 64) {
        int i = base + lane;
        int my = (i < deg) ? tmp_eid[r0 + i] : 0x7fffffff;
        int rank = 0;
        for (int b2 = 0; b2 < deg; b2 += 64) {
            int other = (b2 + lane < deg) ? tmp_eid[r0 + b2 + lane] : 0x7fffffff;
            int cnt2 = min(deg - b2, 64);
            for (int j = 0; j < cnt2; ++j) {
                int oj = __shfl(other, j);
                rank += (oj < my) ? 1 : 0;
            }
        }
        if (i < deg) csr_src[r0 + rank] = src[my];
    }
}

// ---------------- f32 tiled GEMM (layer 1): 32x32 tiles (752 blocks) ----------

#define GM 32
#define GN 32
#define GK 32

__global__ __launch_bounds__(256) void gemm_f32(const float* __restrict__ A,
                                                const float* __restrict__ B,
                                                float* __restrict__ C,
                                                int M, int N, int K) {
    __shared__ float As[GK][GM + 2];
    __shared__ float Bs[GK][GN + 2];
    int t = threadIdx.x;
    int col0 = blockIdx.x * GN, row0 = blockIdx.y * GM;
    int tx = t & 15, ty = t >> 4;
    int am = t >> 3, ak = (t & 7) * 4;
    int bk = t >> 3, bn = (t & 7) * 4;
    float acc[2][2] = {};
    for (int k0 = 0; k0 < K; k0 += GK) {
        int gr = row0 + am;
        float4 av = (gr < M) ? *(const float4*)&A[(size_t)gr * K + k0 + ak]
                             : make_float4(0.f, 0.f, 0.f, 0.f);
        float4 bv = *(const float4*)&B[(size_t)(k0 + bk) * N + col0 + bn];
        __syncthreads();
        As[ak + 0][am] = av.x; As[ak + 1][am] = av.y;
        As[ak + 2][am] = av.z; As[ak + 3][am] = av.w;
        *(float4*)&Bs[bk][bn] = bv;
        __syncthreads();
        #pragma unroll
        for (int kk = 0; kk < GK; ++kk) {
            float2 a2 = *(const float2*)&As[kk][ty * 2];
            float2 b2 = *(const float2*)&Bs[kk][tx * 2];
            acc[0][0] = fmaf(a2.x, b2.x, acc[0][0]);
            acc[0][1] = fmaf(a2.x, b2.y, acc[0][1]);
            acc[1][0] = fmaf(a2.y, b2.x, acc[1][0]);
            acc[1][1] = fmaf(a2.y, b2.y, acc[1][1]);
        }
    }
    #pragma unroll
    for (int i = 0; i < 2; ++i) {
        int gr = row0 + ty * 2 + i;
        if (gr < M) {
            float2 v = make_float2(acc[i][0], acc[i][1]);
            *(float2*)&C[(size_t)gr * N + col0 + tx * 2] = v;
        }
    }
}

// ---------------- el/er kernels ----------------

__global__ void elr_feat_kernel(const float* __restrict__ feat, const float* __restrict__ al,
                                const float* __restrict__ ar, float* __restrict__ el,
                                float* __restrict__ er, int RH) {
    int idx = blockIdx.x * blockDim.x + threadIdx.x;
    if (idx >= RH) return;
    int h = idx & (HEADS - 1);
    const float* fp = feat + (size_t)idx * HIDDEN;
    float sl = 0.f, sr = 0.f;
    for (int f = 0; f < HIDDEN; ++f) {
        float v = fp[f];
        sl = fmaf(v, al[h * HIDDEN + f], sl);
        sr = fmaf(v, ar[h * HIDDEN + f], sr);
    }
    el[idx] = sl;
    er[idx] = sr;
}

__global__ void elr_row_kernel(const float* __restrict__ X, const float* __restrict__ alv,
                               const float* __restrict__ arv, float* __restrict__ el,
                               float* __restrict__ er, int R) {
    int r = blockIdx.x * blockDim.x + threadIdx.x;
    if (r >= R) return;
    const float4* x4 = (const float4*)(X + (size_t)r * 64);
    float sl[8] = {}, sr[8] = {};
    for (int kg = 0; kg < 16; ++kg) {
        float4 xv = x4[kg];
        #pragma unroll
        for (int h = 0; h < 8; ++h) {
            float4 a = *(const float4*)&alv[h * 64 + kg * 4];
            float4 b = *(const float4*)&arv[h * 64 + kg * 4];
            sl[h] = fmaf(xv.x, a.x, fmaf(xv.y, a.y, fmaf(xv.z, a.z, fmaf(xv.w, a.w, sl[h]))));
            sr[h] = fmaf(xv.x, b.x, fmaf(xv.y, b.y, fmaf(xv.z, b.z, fmaf(xv.w, b.w, sr[h]))));
        }
    }
    float* elp = el + (size_t)r * 8;
    float* erp = er + (size_t)r * 8;
    #pragma unroll
    for (int h = 0; h < 8; ++h) { elp[h] = sl[h]; erp[h] = sr[h]; }
}

__device__ __forceinline__ float gelu_exact(float v) {
    return 0.5f * v * (1.0f + erff(v * 0.70710678118654752440f));
}

// ---------------- layer-1 aggregation: wave per (node, head-pair), src in registers ----------
__global__ __launch_bounds__(256) void agg_l1(
    const float* __restrict__ feat, const float* __restrict__ el, const float* __restrict__ er,
    const float* __restrict__ bias, const int* __restrict__ row_ptr,
    const int* __restrict__ csr_src, float* __restrict__ out) {
    int n = blockIdx.x;
    int t = threadIdx.x, wv = t >> 6, lane = t & 63;
    int h0 = 2 * wv;
    int r0 = row_ptr[n], deg = row_ptr[n + 1] - r0;
    float2 erv = *(const float2*)&er[n * 8 + h0];
    float den0 = 0.f, den1 = 0.f, a0 = 0.f, a1 = 0.f;
    for (int c0 = 0; c0 < deg; c0 += 64) {
        int cnt = min(deg - c0, 64);
        int src_r = (lane < cnt) ? csr_src[r0 + c0 + lane] : 0;
        auto do_edge = [&](int s) {
            float2 elv = *(const float2*)&el[s * 8 + h0];
            float x0 = feat[((size_t)s * 8 + h0) * 64 + lane];
            float x1 = feat[((size_t)s * 8 + h0 + 1) * 64 + lane];
            float e0 = elv.x + erv.x; e0 = e0 > 0.f ? e0 : 0.2f * e0;
            float e1 = elv.y + erv.y; e1 = e1 > 0.f ? e1 : 0.2f * e1;
            float w0 = __expf(e0), w1 = __expf(e1);
            den0 += w0; den1 += w1;
            a0 = fmaf(w0, x0, a0);
            a1 = fmaf(w1, x1, a1);
        };
        int i = 0;
        for (; i + 2 <= cnt; i += 2) {
            int s0 = __builtin_amdgcn_readlane(src_r, i);
            int s1 = __builtin_amdgcn_readlane(src_r, i + 1);
            do_edge(s0);
            do_edge(s1);
        }
        if (i < cnt) do_edge(__builtin_amdgcn_readlane(src_r, i));
    }
    float i0 = deg ? 1.f / den0 : 0.f;
    float i1 = deg ? 1.f / den1 : 0.f;
    float v0 = a0 * i0 + bias[h0 * 64 + lane];
    float v1 = a1 * i1 + bias[(h0 + 1) * 64 + lane];
    out[((size_t)n * 8 + h0) * 64 + lane] = gelu_exact(v0);
    out[((size_t)n * 8 + h0 + 1) * 64 + lane] = gelu_exact(v1);
}

// ---------------- layer 2: LDS-staged weights + single-pass transform (KSPLIT=1) ----------
// LDS: inv 0.25K + acc_s 17.4K + wp 17.4K = 35.1 KB -> 4 blocks/CU.
// Phase T: thread (h, ft) computes 2 outputs over ALL 16 kg (no partial reduction).
__global__ __launch_bounds__(256, 4) void agg_fused5(
    const float* __restrict__ X,     // h1 [N*8, 64]
    const float* __restrict__ el, const float* __restrict__ er,  // [N*8, 8]
    const float* __restrict__ W4t,   // [16][512][4]
    const float* __restrict__ bias,  // [512]
    const int* __restrict__ row_ptr, const int* __restrict__ csr_src,
    float* __restrict__ out)         // [N*8, 512]
{
    constexpr int TOT = 512;
    constexpr int PTS = 68;
    constexpr int CHUNK = 64;

    int n = blockIdx.x;
    int r0 = row_ptr[n], deg = row_ptr[n + 1] - r0;
    int t = threadIdx.x, wv = t >> 6, lane = t & 63;

    __shared__ float inv_s[64];
    __shared__ float acc_s[8][8][68];
    __shared__ float wp_lds[64 * PTS];   // weights (64x64 used) | partials (8pl x 8h x 68)

    float agg0[8], agg1[8];
    #pragma unroll
    for (int h = 0; h < 8; ++h) { agg0[h] = 0.f; agg1[h] = 0.f; }
    float den = 0.f;

    int elbase_n = n * 8 * 8;
    int pA = wv * 2;
    float erv_t = er[elbase_n + lane];

    for (int c0 = 0; c0 < deg; c0 += CHUNK) {
        int cnt = min(deg - c0, CHUNK);
        int src_r = (lane < cnt) ? csr_src[r0 + c0 + lane] : 0;
        __syncthreads();
        for (int j = t; j < cnt * 64; j += 256) {
            int i = j >> 6;
            int s = __builtin_amdgcn_readlane(src_r, i);
            float e = el[(s * 8) * 8 + lane] + erv_t;
            e = e > 0.f ? e : 0.2f * e;
            wp_lds[i * 64 + lane] = __expf(e);
        }
        __syncthreads();
        if (t < 64) {
            for (int i = 0; i < cnt; ++i) den += wp_lds[i * 64 + t];
        }
        auto edge_fma = [&](int i) {
            int s = __builtin_amdgcn_readlane(src_r, i);
            const float* wp = &wp_lds[i * 64 + wv * 16];
            float4 w0 = *(const float4*)wp;
            float4 w1 = *(const float4*)(wp + 4);
            float4 w2 = *(const float4*)(wp + 8);
            float4 w3 = *(const float4*)(wp + 12);
            int xb = (s * 8 + pA) * 64 + lane;
            float xv0 = X[xb];
            float xv1 = X[xb + 64];
            agg0[0] = fmaf(w0.x, xv0, agg0[0]);
            agg0[1] = fmaf(w0.y, xv0, agg0[1]);
            agg0[2] = fmaf(w0.z, xv0, agg0[2]);
            agg0[3] = fmaf(w0.w, xv0, agg0[3]);
            agg0[4] = fmaf(w1.x, xv0, agg0[4]);
            agg0[5] = fmaf(w1.y, xv0, agg0[5]);
            agg0[6] = fmaf(w1.z, xv0, agg0[6]);
            agg0[7] = fmaf(w1.w, xv0, agg0[7]);
            agg1[0] = fmaf(w2.x, xv1, agg1[0]);
            agg1[1] = fmaf(w2.y, xv1, agg1[1]);
            agg1[2] = fmaf(w2.z, xv1, agg1[2]);
            agg1[3] = fmaf(w2.w, xv1, agg1[3]);
            agg1[4] = fmaf(w3.x, xv1, agg1[4]);
            agg1[5] = fmaf(w3.y, xv1, agg1[5]);
            agg1[6] = fmaf(w3.z, xv1, agg1[6]);
            agg1[7] = fmaf(w3.w, xv1, agg1[7]);
        };
        int i = 0;
        for (; i + 2 <= cnt; i += 2) { edge_fma(i); edge_fma(i + 1); }
        if (i < cnt) edge_fma(i);
    }
    if (t < 64) inv_s[t] = deg ? 1.f / den : 0.f;
    __syncthreads();
    {
        int pl0 = wv * 2;
        #pragma unroll
        for (int h = 0; h < 8; ++h) {
            acc_s[pl0][h][lane] = agg0[h] * inv_s[pl0 * 8 + h];
            acc_s[pl0 + 1][h][lane] = agg1[h] * inv_s[pl0 * 8 + 8 + h];
        }
    }
    __syncthreads();

    // Phase T: thread = (h = t>>5, ft = t&31); 2 outputs f0 = ft*2, all 16 kg.
    {
        int h = t >> 5, ft = t & 31;
        int f0 = ft * 2;
        float part[8][2];
        #pragma unroll
        for (int pl = 0; pl < 8; ++pl) { part[pl][0] = 0.f; part[pl][1] = 0.f; }
        #pragma unroll
        for (int kg = 0; kg < 16; ++kg) {
            float4 wr0 = *(const float4*)&W4t[(size_t)(kg * TOT + h * 64 + f0 + 0) * 4];
            float4 wr1 = *(const float4*)&W4t[(size_t)(kg * TOT + h * 64 + f0 + 1) * 4];
            #pragma unroll
            for (int pl = 0; pl < 8; ++pl) {
                float4 a4 = *(const float4*)&acc_s[pl][h][kg * 4];
                part[pl][0] = fmaf(a4.x, wr0.x, fmaf(a4.y, wr0.y,
                              fmaf(a4.z, wr0.z, fmaf(a4.w, wr0.w, part[pl][0]))));
                part[pl][1] = fmaf(a4.x, wr1.x, fmaf(a4.y, wr1.y,
                              fmaf(a4.z, wr1.z, fmaf(a4.w, wr1.w, part[pl][1]))));
            }
        }
        __syncthreads();   // weights buffer dead; reuse as partials
        #pragma unroll
        for (int pl = 0; pl < 8; ++pl)
            *(float2*)&wp_lds[(pl * 8 + h) * PTS + f0] = make_float2(part[pl][0], part[pl][1]);
    }
    __syncthreads();

    // Phase R: bias + gelu + coalesced float4 store
    {
        for (int q = t; q < 1024; q += 256) {
            int pl = q >> 7, rem = q & 127;
            int h = rem >> 4, fq = rem & 15;
            int f0 = fq * 4;
            float4 acc4 = *(const float4*)&wp_lds[(pl * 8 + h) * PTS + f0];
            float4 b4 = *(const float4*)&bias[h * 64 + f0];
            acc4.x = gelu_exact(acc4.x + b4.x);
            acc4.y = gelu_exact(acc4.y + b4.y);
            acc4.z = gelu_exact(acc4.z + b4.z);
            acc4.w = gelu_exact(acc4.w + b4.w);
            *(float4*)&out[(size_t)(n * 8 + pl) * TOT + h * 64 + f0] = acc4;
        }
    }
}

// ---------------- layer 3: register-src aggregation + split-h MFMA transform ----------------
// Block = (node, 16-p group), 6000 blocks. accH = 17.4 KB, VGPR 36 ->
// __launch_bounds__(256,8): 8 blocks/CU (139 KB LDS, 32 waves).
__global__ __launch_bounds__(256, 8) void agg_mfma6(
    const float* __restrict__ X,        // h2 [N*64, 64]
    const float* __restrict__ el, const float* __restrict__ er,  // [N*64, 8]
    const unsigned* __restrict__ wfhi, const unsigned* __restrict__ wflo,
    const float* __restrict__ bias,     // [256]
    const int* __restrict__ row_ptr, const int* __restrict__ csr_src,
    float* __restrict__ out)            // [N*64, 256]
{
    int b = blockIdx.x;                  // 6000 = 1500 n * 4 pg
    int n = b >> 2, pg = b & 3;
    int p0 = pg * 16;
    int r0 = row_ptr[n], deg = row_ptr[n + 1] - r0;
    int t = threadIdx.x, wv = t >> 6, lane = t & 63;
    int pA = p0 + wv * 4;

    __shared__ unsigned accH[4][16][68];   // [h in round][pl][k] packed bf16 hi|lo

    int c = lane & 31;                     // (q,h) = (c>>3, c&7)
    float erv = er[(n * 64 + pA) * 8 + c];

    float agg[4][8];
    #pragma unroll
    for (int q = 0; q < 4; ++q)
        #pragma unroll
        for (int h = 0; h < 8; ++h) agg[q][h] = 0.f;
    float den_half = 0.f;

    for (int c0 = 0; c0 < deg; c0 += 64) {
        int cnt = min(deg - c0, 64);
        int src_r = (lane < cnt) ? csr_src[r0 + c0 + lane] : 0;
        for (int it = 0; it < cnt; it += 4) {
            int i1 = min(it + 1, cnt - 1), i2 = min(it + 2, cnt - 1), i3 = min(it + 3, cnt - 1);
            int s0 = __builtin_amdgcn_readlane(src_r, it);
            int s1 = __builtin_amdgcn_readlane(src_r, i1);
            int s2 = __builtin_amdgcn_readlane(src_r, i2);
            int s3 = __builtin_amdgcn_readlane(src_r, i3);
            bool v1 = it + 1 < cnt, v2 = it + 2 < cnt, v3 = it + 3 < cnt;
            int sA = (lane < 32) ? s0 : s1;
            int sB = (lane < 32) ? s2 : s3;
            float eA = el[(sA * 64 + pA) * 8 + c] + erv;
            float eB = el[(sB * 64 + pA) * 8 + c] + erv;
            eA = eA > 0.f ? eA : 0.2f * eA;
            eB = eB > 0.f ? eB : 0.2f * eB;
            if (lane >= 32 && !v1) eA = -1e30f;
            if (lane < 32 && !v2) eB = -1e30f;
            if (lane >= 32 && !v3) eB = -1e30f;
            float wA = __expf(eA), wB = __expf(eB);
            den_half += wA + wB;
            int xb0 = (s0 * 64 + pA) * 64 + lane;
            int xb1 = (s1 * 64 + pA) * 64 + lane;
            int xb2 = (s2 * 64 + pA) * 64 + lane;
            int xb3 = (s3 * 64 + pA) * 64 + lane;
            float x0[4], x1[4], x2[4], x3[4];
            #pragma unroll
            for (int q = 0; q < 4; ++q) x0[q] = X[xb0 + q * 64];
            #pragma unroll
            for (int q = 0; q < 4; ++q) x1[q] = X[xb1 + q * 64];
            #pragma unroll
            for (int q = 0; q < 4; ++q) x2[q] = X[xb2 + q * 64];
            #pragma unroll
            for (int q = 0; q < 4; ++q) x3[q] = X[xb3 + q * 64];
            #pragma unroll
            for (int q = 0; q < 4; ++q) {
                #pragma unroll
                for (int h = 0; h < 8; ++h) {
                    agg[q][h] = fmaf(rdlanef(wA, q * 8 + h), x0[q], agg[q][h]);
                    agg[q][h] = fmaf(rdlanef(wA, 32 + q * 8 + h), x1[q], agg[q][h]);
                    agg[q][h] = fmaf(rdlanef(wB, q * 8 + h), x2[q], agg[q][h]);
                    agg[q][h] = fmaf(rdlanef(wB, 32 + q * 8 + h), x3[q], agg[q][h]);
                }
            }
        }
    }
    float den = den_half + __shfl(den_half, lane ^ 32);
    float inv = deg ? 1.f / den : 0.f;

    int m16 = lane & 15, g = lane >> 4;
    #pragma unroll
    for (int r = 0; r < 2; ++r) {
        if (r) __syncthreads();   // prev round's MFMA reads done before overwrite
        // pack heads [4r, 4r+4): wave wv packs its 4 p's
        #pragma unroll
        for (int q = 0; q < 4; ++q) {
            int pl = wv * 4 + q;
            #pragma unroll
            for (int hh = 0; hh < 4; ++hh) {
                int h = 4 * r + hh;
                float iv = rdlanef(inv, q * 8 + h);
                accH[hh][pl][lane] = packbf(agg[q][h] * iv);
            }
        }
        __syncthreads();
        // MFMA: wave wv handles head h = 4r + wv
        int h = 4 * r + wv;
        bf16x8 a_hi[2], a_lo[2];
        #pragma unroll
        for (int ks = 0; ks < 2; ++ks) {
            const unsigned* ap = &accH[wv][m16][ks * 32 + g * 8];
            uint4 q0 = *(const uint4*)ap;
            uint4 q1 = *(const uint4*)(ap + 4);
            a_hi[ks][0] = (short)(q0.x & 0xffffu); a_lo[ks][0] = (short)(q0.x >> 16);
            a_hi[ks][1] = (short)(q0.y & 0xffffu); a_lo[ks][1] = (short)(q0.y >> 16);
            a_hi[ks][2] = (short)(q0.z & 0xffffu); a_lo[ks][2] = (short)(q0.z >> 16);
            a_hi[ks][3] = (short)(q0.w & 0xffffu); a_lo[ks][3] = (short)(q0.w >> 16);
            a_hi[ks][4] = (short)(q1.x & 0xffffu); a_lo[ks][4] = (short)(q1.x >> 16);
            a_hi[ks][5] = (short)(q1.y & 0xffffu); a_lo[ks][5] = (short)(q1.y >> 16);
            a_hi[ks][6] = (short)(q1.z & 0xffffu); a_lo[ks][6] = (short)(q1.z >> 16);
            a_hi[ks][7] = (short)(q1.w & 0xffffu); a_lo[ks][7] = (short)(q1.w >> 16);
        }
        #pragma unroll
        for (int nt = 0; nt < 2; ++nt) {
            f32x4 D = {0.f, 0.f, 0.f, 0.f};
            #pragma unroll
            for (int ks = 0; ks < 2; ++ks) {
                size_t fb = (size_t)(((h * 2 + nt) * 2 + ks) * 64 + lane) * 4;
                bf16x8 b_hi = *(const bf16x8*)&wfhi[fb];
                bf16x8 b_lo = *(const bf16x8*)&wflo[fb];
                D = __builtin_amdgcn_mfma_f32_16x16x32_bf16(a_hi[ks], b_hi, D, 0, 0, 0);
                D = __builtin_amdgcn_mfma_f32_16x16x32_bf16(a_hi[ks], b_lo, D, 0, 0, 0);
                D = __builtin_amdgcn_mfma_f32_16x16x32_bf16(a_lo[ks], b_hi, D, 0, 0, 0);
            }
            float bv = bias[h * 32 + nt * 16 + m16];
            size_t ob = ((size_t)(n * 64) + p0 + g * 4) * 256 + h * 32 + nt * 16 + m16;
            out[ob]       = D[0] + bv;
            out[ob + 256] = D[1] + bv;
            out[ob + 512] = D[2] + bv;
            out[ob + 768] = D[3] + bv;
        }
    }
}

// ---------------- launch ----------------

extern "C" void kernel_launch(void* const* d_in, const int* in_sizes, int n_in,
                              void* d_out, int out_size, void* d_ws, size_t ws_size,
                              hipStream_t stream) {
    const float* node = (const float*)d_in[0];
    const int* src = (const int*)d_in[1];
    const int* dst = (const int*)d_in[2];
    const float* W1 = (const float*)d_in[3];
    const float* al1 = (const float*)d_in[4];
    const float* ar1 = (const float*)d_in[5];
    const float* b1 = (const float*)d_in[6];
    const float* W2 = (const float*)d_in[7];
    const float* al2 = (const float*)d_in[8];
    const float* ar2 = (const float*)d_in[9];
    const float* b2 = (const float*)d_in[10];
    const float* W3 = (const float*)d_in[11];
    const float* al3 = (const float*)d_in[12];
    const float* ar3 = (const float*)d_in[13];
    const float* b3 = (const float*)d_in[14];
    float* out = (float*)d_out;

    char* ws = (char*)d_ws;
    size_t off = 0;
    auto alloc = [&](size_t nb) -> char* {
        char* q = ws + off;
        off += (nb + 255) & ~(size_t)255;
        return q;
    };
    int* counts   = (int*)alloc((N_NODES + 1) * sizeof(int));
    int* cursor   = (int*)alloc(N_NODES * sizeof(int));
    int* row_ptr  = (int*)alloc((N_NODES + 1) * sizeof(int));
    int* tmp_eid  = (int*)alloc(N_EDGES * sizeof(int));
    int* csr_src  = (int*)alloc(N_EDGES * sizeof(int));
    float* feat1  = (float*)alloc((size_t)N_NODES * 8 * 64 * 4);
    float* el1    = (float*)alloc((size_t)N_NODES * 8 * 4);
    float* er1    = (float*)alloc((size_t)N_NODES * 8 * 4);
    float* h1     = (float*)alloc((size_t)N_NODES * 8 * 64 * 4);
    float* aleff2 = (float*)alloc(8 * 64 * 4);
    float* areff2 = (float*)alloc(8 * 64 * 4);
    float* el2    = (float*)alloc((size_t)N_NODES * 8 * 8 * 4);
    float* er2    = (float*)alloc((size_t)N_NODES * 8 * 8 * 4);
    float* h2     = (float*)alloc((size_t)N_NODES * 64 * 64 * 4);
    float* aleff3 = (float*)alloc(8 * 64 * 4);
    float* areff3 = (float*)alloc(8 * 64 * 4);
    float* el3    = (float*)alloc((size_t)N_NODES * 64 * 8 * 4);
    float* er3    = (float*)alloc((size_t)N_NODES * 64 * 8 * 4);
    float* W4t2   = (float*)alloc((size_t)16 * 512 * 4 * 4);
    unsigned* wfhi = (unsigned*)alloc((size_t)8192 * 4);
    unsigned* wflo = (unsigned*)alloc((size_t)8192 * 4);

    const int PREP_T = 1536 + 1536 + 1024 + 1024 + 16 * 512 * 4 + 16384;
    prep_kernel<<<(PREP_T + 255) / 256, 256, 0, stream>>>(
        W2, al2, ar2, W3, al3, ar3, aleff2, areff2, aleff3, areff3, W4t2, wfhi, wflo,
        counts, cursor);

    hist_kernel<<<(N_EDGES + 255) / 256, 256, 0, stream>>>(dst, counts);
    scan_kernel<<<1, 256, 0, stream>>>(counts, row_ptr);
    scatter_kernel<<<(N_EDGES + 255) / 256, 256, 0, stream>>>(dst, row_ptr, cursor, tmp_eid);
    sort_csr_kernel<<<(N_NODES * 64 + 255) / 256, 256, 0, stream>>>(row_ptr, tmp_eid, src, csr_src);

    // ---- layer 1 ----
    dim3 g1((512 + GN - 1) / GN, (N_NODES + GM - 1) / GM);
    gemm_f32<<<g1, 256, 0, stream>>>(node, W1, feat1, N_NODES, 512, IN_FEAT);
    elr_feat_kernel<<<(N_NODES * 8 + 255) / 256, 256, 0, stream>>>(feat1, al1, ar1, el1, er1, N_NODES * 8);
    agg_l1<<<N_NODES, 256, 0, stream>>>(feat1, el1, er1, b1, row_ptr, csr_src, h1);

    // ---- layer 2 ----
    elr_row_kernel<<<(N_NODES * 8 + 255) / 256, 256, 0, stream>>>(h1, aleff2, areff2, el2, er2, N_NODES * 8);
    agg_fused5<<<N_NODES, 256, 0, stream>>>(h1, el2, er2, W4t2, b2, row_ptr, csr_src, h2);

    // ---- layer 3 ----
    elr_row_kernel<<<(N_NODES * 64 + 255) / 256, 256, 0, stream>>>(h2, aleff3, areff3, el3, er3, N_NODES * 64);
    agg_mfma6<<<N_NODES * 4, 256, 0, stream>>>(h2, el3, er3, wfhi, wflo, b3, row_ptr, csr_src, out);
}